// Round 5
// baseline (20854.422 us; speedup 1.0000x reference)
//
#include <hip/hip_runtime.h>
#include <hip/hip_bf16.h>
#include <stdint.h>

#define TT 64
#define BB 512
#define XX 1024
#define HH 1024
#define ZZ 256
#define AA 64

#define NBLK 256
#define NTHR 512

typedef __bf16 bf16;
typedef bf16 bf16x8 __attribute__((ext_vector_type(8)));
typedef float f32x4 __attribute__((ext_vector_type(4)));

// d_out layout (fp32): beliefs[T+1,B,H] | q_loc | q_scale | p_loc | p_scale | z_q
#define SZ_BEL ((long)(TT + 1) * BB * HH)
#define SZ_TBZ ((long)TT * BB * ZZ)
#define OFF_QL (SZ_BEL)
#define OFF_QS (OFF_QL + SZ_TBZ)
#define OFF_PL (OFF_QL + 2 * SZ_TBZ)
#define OFF_PS (OFF_QL + 3 * SZ_TBZ)
#define OFF_ZQ (OFF_QL + 4 * SZ_TBZ)

#define GLL16(g, l)                                                         \
  __builtin_amdgcn_global_load_lds(                                         \
      (__attribute__((address_space(1))) void*)(g),                         \
      (__attribute__((address_space(3))) void*)(l), 16, 0, 0)

#define MFMA(a, b, c) __builtin_amdgcn_mfma_f32_16x16x32_bf16(a, b, c, 0, 0, 0)

__device__ __forceinline__ float eluf(float x) { return x > 0.f ? x : expf(x) - 1.f; }
__device__ __forceinline__ float splusf(float x) { return fmaxf(x, 0.f) + log1pf(expf(-fabsf(x))); }
__device__ __forceinline__ float sigf(float x) { return 1.f / (1.f + expf(-x)); }

// ---------------- persistent scan kernel (no LDS, register-streamed frags) ---

struct ScanArgs {
  const bf16 *Pq1, *Pqh, *Pag, *Pih, *Phh;  // frag-linear packed weights
  const bf16 *obs_preT, *act_bf;
  bf16 *h_bf, *hid_q, *z_bf, *a_buf;
  const float *b_q1, *b_ghh, *b_qm, *b_qs, *b_ag, *b_gih;
  const float* eps;
  float* dout;
  unsigned* bar;
};

// Two-level tree barrier (16 leaves x 16 adders -> root), from round 4.
__device__ __forceinline__ void gsync(unsigned* bar, unsigned& gen) {
  __syncthreads();
  ++gen;
  if (threadIdx.x == 0) {
    __threadfence();
    const int bid = blockIdx.x;
    unsigned* lf = bar + (bid >> 4) * 32;
    unsigned* root = bar + 512;
    atomicAdd(lf, 1u);
    if ((bid & 15) == 0) {
      while (__hip_atomic_load(lf, __ATOMIC_RELAXED, __HIP_MEMORY_SCOPE_AGENT) < 16u * gen)
        __builtin_amdgcn_s_sleep(1);
      atomicAdd(root, 1u);
    }
    while (__hip_atomic_load(root, __ATOMIC_RELAXED, __HIP_MEMORY_SCOPE_AGENT) < 16u * gen)
      __builtin_amdgcn_s_sleep(1);
  }
  __syncthreads();
  __threadfence();
}

__device__ __forceinline__ bf16x8 ldg8(const bf16* p) { return *(const bf16x8*)p; }

__global__ __launch_bounds__(NTHR, 2) void scan_k(ScanArgs s) {
  const int bid = blockIdx.x, tid = threadIdx.x;
  const int wid = tid >> 6, lane = tid & 63;
  const int lr = lane & 15, lk = lane >> 4;
  unsigned gen = 0;
  const int isR = bid >= 128;
  const int mh = isR ? ((bid - 128) >> 6) : 0;   // m-half (256 rows)
  const int js = isR ? ((bid - 128) & 63) : 0;   // 16-col j-slice
  f32x4 hreg[2] = {f32x4{0.f, 0.f, 0.f, 0.f}, f32x4{0.f, 0.f, 0.f, 0.f}};

  for (int t = 0; t < TT; ++t) {
    f32x4 ghacc[2][3] = {};  // role R: h@Whh accumulators, persist P1 -> P4

    // ===== P1: hid_q (blocks 0-63) | gh (blocks 128-255) ====================
    if (bid < 64) {
      const bf16* ap[4];
#pragma unroll
      for (int i = 0; i < 4; ++i)
        ap[i] = s.h_bf + ((wid * 4 + i) * 16 + lr) * HH + lk * 8;
      const bf16* bp = s.Pq1 + (long)bid * 32 * 512 + lane * 8;
      bf16x8 ar[4][4], br[4];
#pragma unroll
      for (int p = 0; p < 4; ++p) {
#pragma unroll
        for (int i = 0; i < 4; ++i) ar[p][i] = ldg8(ap[i] + p * 32);
        br[p] = ldg8(bp + (long)p * 512);
      }
      f32x4 acc[4] = {};
#pragma unroll
      for (int kt = 0; kt < 32; ++kt) {
        const int sl = kt & 3;
#pragma unroll
        for (int i = 0; i < 4; ++i) acc[i] = MFMA(ar[sl][i], br[sl], acc[i]);
        if (kt + 4 < 32) {
#pragma unroll
          for (int i = 0; i < 4; ++i) ar[sl][i] = ldg8(ap[i] + (kt + 4) * 32);
          br[sl] = ldg8(bp + (long)(kt + 4) * 512);
        }
      }
      const int col = bid * 16 + lr;
#pragma unroll
      for (int i = 0; i < 4; ++i)
#pragma unroll
        for (int r = 0; r < 4; ++r) {
          int row = wid * 64 + i * 16 + lk * 4 + r;
          float x = acc[i][r] + s.b_q1[col] +
                    (float)s.obs_preT[((long)t * HH + col) * BB + row];
          s.hid_q[row * HH + col] = (bf16)eluf(x);
        }
    } else if (isR) {
      const bf16* ap[2];
#pragma unroll
      for (int i = 0; i < 2; ++i)
        ap[i] = s.h_bf + (mh * 256 + wid * 32 + i * 16 + lr) * HH + lk * 8;
      const bf16* bp = s.Phh + (long)js * 3 * 32 * 512 + lane * 8;
      bf16x8 ar[4][2], br[4][3];
#pragma unroll
      for (int p = 0; p < 4; ++p) {
#pragma unroll
        for (int i = 0; i < 2; ++i) ar[p][i] = ldg8(ap[i] + p * 32);
#pragma unroll
        for (int g = 0; g < 3; ++g) br[p][g] = ldg8(bp + (long)(g * 32 + p) * 512);
      }
#pragma unroll
      for (int kt = 0; kt < 32; ++kt) {
        const int sl = kt & 3;
#pragma unroll
        for (int g = 0; g < 3; ++g)
#pragma unroll
          for (int i = 0; i < 2; ++i)
            ghacc[i][g] = MFMA(ar[sl][i], br[sl][g], ghacc[i][g]);
        if (kt + 4 < 32) {
#pragma unroll
          for (int i = 0; i < 2; ++i) ar[sl][i] = ldg8(ap[i] + (kt + 4) * 32);
#pragma unroll
          for (int g = 0; g < 3; ++g)
            br[sl][g] = ldg8(bp + (long)(g * 32 + kt + 4) * 512);
        }
      }
    }
    gsync(s.bar, gen);

    // ===== P2: q-heads dual + rsample (blocks 0-31) =========================
    if (bid < 32) {
      const int j0 = bid * 8;
      const bf16* ap[4];
#pragma unroll
      for (int i = 0; i < 4; ++i)
        ap[i] = s.hid_q + ((wid * 4 + i) * 16 + lr) * HH + lk * 8;
      const bf16* bp = s.Pqh + (long)bid * 32 * 512 + lane * 8;
      bf16x8 ar[4][4], br[4];
#pragma unroll
      for (int p = 0; p < 4; ++p) {
#pragma unroll
        for (int i = 0; i < 4; ++i) ar[p][i] = ldg8(ap[i] + p * 32);
        br[p] = ldg8(bp + (long)p * 512);
      }
      f32x4 acc[4] = {};
#pragma unroll
      for (int kt = 0; kt < 32; ++kt) {
        const int sl = kt & 3;
#pragma unroll
        for (int i = 0; i < 4; ++i) acc[i] = MFMA(ar[sl][i], br[sl], acc[i]);
        if (kt + 4 < 32) {
#pragma unroll
          for (int i = 0; i < 4; ++i) ar[sl][i] = ldg8(ap[i] + (kt + 4) * 32);
          br[sl] = ldg8(bp + (long)(kt + 4) * 512);
        }
      }
#pragma unroll
      for (int i = 0; i < 4; ++i)
#pragma unroll
        for (int r = 0; r < 4; ++r) {
          int row = wid * 64 + i * 16 + lk * 4 + r;
          float myv = acc[i][r] + ((lr < 8) ? s.b_qm[j0 + lr] : s.b_qs[j0 + lr - 8]);
          float sc_all = splusf(myv);
          float sc = __shfl(sc_all, lane + 8, 64);
          if (lr < 8) {
            long o = ((long)t * BB + row) * ZZ + j0 + lr;
            float z = myv + sc * s.eps[o];
            s.dout[OFF_QL + o] = myv;
            s.dout[OFF_ZQ + o] = z;
            s.z_bf[row * ZZ + j0 + lr] = (bf16)z;
          } else {
            long o = ((long)t * BB + row) * ZZ + j0 + lr - 8;
            s.dout[OFF_QS + o] = sc_all;
          }
        }
    }
    gsync(s.bar, gen);

    // ===== P3: a = elu([z|act] @ aggrW + b)  (blocks 64-127) ================
    if (bid >= 64 && bid < 128) {
      const int c0 = (bid - 64) * 16;
      int rowb[4];
#pragma unroll
      for (int i = 0; i < 4; ++i) rowb[i] = (wid * 4 + i) * 16 + lr;
      const bf16* bp = s.Pag + (long)(bid - 64) * 10 * 512 + lane * 8;
      bf16x8 ar[4][4], br[4];
#pragma unroll
      for (int p = 0; p < 4; ++p) {
#pragma unroll
        for (int i = 0; i < 4; ++i)
          ar[p][i] = ldg8(s.z_bf + rowb[i] * ZZ + p * 32 + lk * 8);
        br[p] = ldg8(bp + (long)p * 512);
      }
      f32x4 acc[4] = {};
#pragma unroll
      for (int kt = 0; kt < 10; ++kt) {
        const int sl = kt & 3;
#pragma unroll
        for (int i = 0; i < 4; ++i) acc[i] = MFMA(ar[sl][i], br[sl], acc[i]);
        if (kt + 4 < 10) {
          const int kn = kt + 4;
#pragma unroll
          for (int i = 0; i < 4; ++i) {
            const bf16* src = (kn < 8)
                ? s.z_bf + rowb[i] * ZZ + kn * 32 + lk * 8
                : s.act_bf + ((long)t * BB + rowb[i]) * AA + (kn - 8) * 32 + lk * 8;
            ar[sl][i] = ldg8(src);
          }
          br[sl] = ldg8(bp + (long)kn * 512);
        }
      }
#pragma unroll
      for (int i = 0; i < 4; ++i)
#pragma unroll
        for (int r = 0; r < 4; ++r) {
          int row = wid * 64 + i * 16 + lk * 4 + r;
          int col = c0 + lr;
          s.a_buf[row * HH + col] = (bf16)eluf(acc[i][r] + s.b_ag[col]);
        }
    }
    gsync(s.bar, gen);

    // ===== P4: gi = a @ Wih + in-register GRU fuse (blocks 128-255) =========
    if (isR) {
      const bf16* ap[2];
#pragma unroll
      for (int i = 0; i < 2; ++i)
        ap[i] = s.a_buf + (mh * 256 + wid * 32 + i * 16 + lr) * HH + lk * 8;
      const bf16* bp = s.Pih + (long)js * 3 * 32 * 512 + lane * 8;
      bf16x8 ar[4][2], br[4][3];
#pragma unroll
      for (int p = 0; p < 4; ++p) {
#pragma unroll
        for (int i = 0; i < 2; ++i) ar[p][i] = ldg8(ap[i] + p * 32);
#pragma unroll
        for (int g = 0; g < 3; ++g) br[p][g] = ldg8(bp + (long)(g * 32 + p) * 512);
      }
      f32x4 gi[2][3] = {};
#pragma unroll
      for (int kt = 0; kt < 32; ++kt) {
        const int sl = kt & 3;
#pragma unroll
        for (int g = 0; g < 3; ++g)
#pragma unroll
          for (int i = 0; i < 2; ++i)
            gi[i][g] = MFMA(ar[sl][i], br[sl][g], gi[i][g]);
        if (kt + 4 < 32) {
#pragma unroll
          for (int i = 0; i < 2; ++i) ar[sl][i] = ldg8(ap[i] + (kt + 4) * 32);
#pragma unroll
          for (int g = 0; g < 3; ++g)
            br[sl][g] = ldg8(bp + (long)(g * 32 + kt + 4) * 512);
        }
      }
      const int j = js * 16 + lr;
#pragma unroll
      for (int i = 0; i < 2; ++i)
#pragma unroll
        for (int r = 0; r < 4; ++r) {
          int row = mh * 256 + wid * 32 + i * 16 + lk * 4 + r;
          float ir = gi[i][0][r] + s.b_gih[j] + ghacc[i][0][r] + s.b_ghh[j];
          float iz = gi[i][1][r] + s.b_gih[HH + j] + ghacc[i][1][r] + s.b_ghh[HH + j];
          float inn = gi[i][2][r] + s.b_gih[2 * HH + j];
          float hnn = ghacc[i][2][r] + s.b_ghh[2 * HH + j];
          float rr = sigf(ir), zz = sigf(iz);
          float nn = tanhf(inn + rr * hnn);
          float hold = hreg[i][r];
          float hnew = (1.f - zz) * nn + zz * hold;
          hreg[i][r] = hnew;
          s.h_bf[row * HH + j] = (bf16)hnew;
          s.dout[(long)(t + 1) * BB * HH + (long)row * HH + j] = hnew;
        }
    }
    gsync(s.bar, gen);
  }
}

// ---------------- weight packing (frag-linear) -------------------------------
// dst[((f*kts + kt)*64 + l)*8 + e] = W[(row0 + kt*32 + (l>>4)*8 + e)*ld + col],
// col = (f%gmod)*gstride + (f/gmod)*16 + (l&15)
__global__ void pack16(const float* __restrict__ W, bf16* __restrict__ dst,
                       int ld, int row0, int kts, int kmax, long total,
                       int gmod, int gstride) {
  long idx = (long)blockIdx.x * 256 + threadIdx.x;
  if (idx >= total) return;
  int l = (int)(idx & 63);
  long fk = idx >> 6;
  int kt = (int)(fk % kts);
  int f = (int)(fk / kts);
  int col = (f % gmod) * gstride + (f / gmod) * 16 + (l & 15);
  int k = kt * 32 + (l >> 4) * 8;
  bf16x8 v;
#pragma unroll
  for (int e = 0; e < 8; ++e) {
    int kk = k + e;
    v[e] = (bf16)((kk < kmax) ? W[(long)(row0 + kk) * ld + col] : 0.f);
  }
  *(bf16x8*)&dst[idx * 8] = v;
}

// dual loc/scale frag: cols 0-7 from Wm[:, f*8..], 8-15 from Ws[:, f*8..]
__global__ void pack_qh(const float* __restrict__ Wm, const float* __restrict__ Ws,
                        bf16* __restrict__ dst) {
  long idx = (long)blockIdx.x * 256 + threadIdx.x;  // 32*32*64
  int l = (int)(idx & 63);
  long fk = idx >> 6;
  int kt = (int)(fk & 31);
  int f = (int)(fk >> 5);
  (void)kt;
  int k = (int)((fk & 31) * 32) + (l >> 4) * 8;
  const float* W = ((l & 15) < 8) ? Wm : Ws;
  int col = f * 8 + (l & 7);
  bf16x8 v;
#pragma unroll
  for (int e = 0; e < 8; ++e) v[e] = (bf16)W[(long)(k + e) * 256 + col];
  *(bf16x8*)&dst[idx * 8] = v;
}

// ---------------- batched GEMMs (prep / tails) ----------------

struct GArgs {
  const bf16* A; const float* Af;
  long lda;
  const bf16* Bt;
  int M, N, K;
  const float *b_p1, *b_pm, *b_ps;
  bf16* out_bf;
  float* dout;
};

// EPI: 5 = elu+bias -> bf16   6 = p-heads -> d_out   7 = bf16 transposed [t][col][row]
template <int BM, int BN, int EPI, bool AF32>
__global__ __launch_bounds__(256) void gemm_k(GArgs g) {
  constexpr int BK = 32;
  constexpr int WTM = BM / 2, WTN = BN / 2;
  constexpr int MR = WTM / 16, NR = WTN / 16;
  constexpr int CA = BM * 4 / 256, CB = BN * 4 / 256;
  __shared__ bf16 sA[BM * BK];
  __shared__ bf16 sB[BN * BK];
  const int nbm = g.M / BM;
  const int bm = blockIdx.x % nbm, bn = blockIdx.x / nbm;
  const int m0 = bm * BM, n0 = bn * BN;
  const int tid = threadIdx.x;
  const int wid = tid >> 6, lane = tid & 63;
  const int wm = wid & 1, wn = wid >> 1;
  const int lr = lane & 15, lk = lane >> 4;

  f32x4 acc[MR][NR] = {};

  for (int k0 = 0; k0 < g.K; k0 += BK) {
    __syncthreads();
    if constexpr (AF32) {
#pragma unroll
      for (int i = 0; i < CA; i++) {
        int c = tid + i * 256, row = c >> 2, kc = c & 3;
        const float* sp = g.Af + (long)(m0 + row) * g.lda + k0 + kc * 8;
        float4 v0 = *(const float4*)sp;
        float4 v1 = *(const float4*)(sp + 4);
        bf16x8 p;
        p[0] = (bf16)v0.x; p[1] = (bf16)v0.y; p[2] = (bf16)v0.z; p[3] = (bf16)v0.w;
        p[4] = (bf16)v1.x; p[5] = (bf16)v1.y; p[6] = (bf16)v1.z; p[7] = (bf16)v1.w;
        *(bf16x8*)&sA[c * 8] = p;
      }
    } else {
#pragma unroll
      for (int i = 0; i < CA; i++) {
        int c = tid + i * 256, row = c >> 2, kc = c & 3;
        GLL16(g.A + (long)(m0 + row) * g.lda + k0 + kc * 8, &sA[c * 8]);
      }
    }
#pragma unroll
    for (int i = 0; i < CB; i++) {
      int c = tid + i * 256, row = c >> 2, kc = c & 3;
      GLL16(g.Bt + (long)(n0 + row) * g.K + k0 + kc * 8, &sB[c * 8]);
    }
    __syncthreads();
    bf16x8 af[MR];
#pragma unroll
    for (int mi = 0; mi < MR; mi++)
      af[mi] = *(const bf16x8*)&sA[(wm * WTM + mi * 16 + lr) * BK + lk * 8];
#pragma unroll
    for (int nj = 0; nj < NR; nj++) {
      bf16x8 bfr = *(const bf16x8*)&sB[(wn * WTN + nj * 16 + lr) * BK + lk * 8];
#pragma unroll
      for (int mi = 0; mi < MR; mi++)
        acc[mi][nj] = MFMA(af[mi], bfr, acc[mi][nj]);
    }
  }

#pragma unroll
  for (int mi = 0; mi < MR; mi++)
#pragma unroll
    for (int nj = 0; nj < NR; nj++)
#pragma unroll
      for (int r = 0; r < 4; r++) {
        const int row = m0 + wm * WTM + mi * 16 + lk * 4 + r;
        const int col = n0 + wn * WTN + nj * 16 + lr;
        float v = acc[mi][nj][r];
        if constexpr (EPI == 7) {
          g.out_bf[((long)(row >> 9) * HH + col) * BB + (row & 511)] = (bf16)v;
        } else if constexpr (EPI == 5) {
          g.out_bf[(long)row * g.N + col] = (bf16)eluf(v + g.b_p1[col]);
        } else {
          int region = col >> 8, j = col & 255;
          float x = v + (region ? g.b_ps[j] : g.b_pm[j]);
          if (region) x = splusf(x);
          g.dout[(region ? OFF_PS : OFF_PL) + (long)row * ZZ + j] = x;
        }
      }
}

// dst[n*K + k] = bf16(src[(k + k_off)*ld + n]); grid (N/32, K/32), block (32,8)
__global__ void transpose_cvt(const float* __restrict__ src, bf16* __restrict__ dst,
                              int K, int N, int ld, int k_off) {
  __shared__ float tile[32][33];
  const int nb = blockIdx.x * 32, kb = blockIdx.y * 32;
  const int tx = threadIdx.x, ty = threadIdx.y;
#pragma unroll
  for (int j = 0; j < 32; j += 8)
    tile[ty + j][tx] = src[(long)(kb + ty + j + k_off) * ld + nb + tx];
  __syncthreads();
#pragma unroll
  for (int j = 0; j < 32; j += 8)
    dst[(long)(nb + ty + j) * K + kb + tx] = (bf16)tile[tx][ty + j];
}

__global__ void cvt_bf16(const float* __restrict__ src, bf16* __restrict__ dst, long n) {
  long i = ((long)blockIdx.x * blockDim.x + threadIdx.x) * 4;
  if (i < n) {
    float4 v = *(const float4*)(src + i);
    dst[i] = (bf16)v.x; dst[i + 1] = (bf16)v.y;
    dst[i + 2] = (bf16)v.z; dst[i + 3] = (bf16)v.w;
  }
}

__global__ void init_k(bf16* hbf, float* dout) {
  int i = blockIdx.x * 256 + threadIdx.x;
  hbf[i] = (bf16)0.f;
  dout[i] = 0.f;  // beliefs[0] = h0 = 0
}

extern "C" void kernel_launch(void* const* d_in, const int* in_sizes, int n_in,
                              void* d_out, int out_size, void* d_ws, size_t ws_size,
                              hipStream_t stream) {
  const float* obs  = (const float*)d_in[0];
  const float* act  = (const float*)d_in[1];
  const float* eps  = (const float*)d_in[2];
  const float* aggrW = (const float*)d_in[3];
  const float* aggrB = (const float*)d_in[4];
  const float* gWih = (const float*)d_in[5];
  const float* gWhh = (const float*)d_in[6];
  const float* gbih = (const float*)d_in[7];
  const float* gbhh = (const float*)d_in[8];
  const float* qW1  = (const float*)d_in[9];
  const float* qb1  = (const float*)d_in[10];
  const float* qWm  = (const float*)d_in[11];
  const float* qbm  = (const float*)d_in[12];
  const float* qWs  = (const float*)d_in[13];
  const float* qbs  = (const float*)d_in[14];
  const float* pW1  = (const float*)d_in[15];
  const float* pb1  = (const float*)d_in[16];
  const float* pWm  = (const float*)d_in[17];
  const float* pbm  = (const float*)d_in[18];
  const float* pWs  = (const float*)d_in[19];
  const float* pbs  = (const float*)d_in[20];
  float* dout = (float*)d_out;

  char* w = (char*)d_ws;
  size_t off = 0;
  auto alloc = [&](size_t bytes) -> char* {
    char* r = w + off;
    off = (off + bytes + 255) & ~(size_t)255;
    return r;
  };
  bf16* Pq1 = (bf16*)alloc((size_t)64 * 32 * 512 * 2);       // q_W1[X:] frag-packed
  bf16* Pqh = (bf16*)alloc((size_t)32 * 32 * 512 * 2);       // [qWm|qWs] dual frags
  bf16* Pag = (bf16*)alloc((size_t)64 * 10 * 512 * 2);       // aggr_W frags
  bf16* Pih = (bf16*)alloc((size_t)192 * 32 * 512 * 2);      // Wih j-sliced frags
  bf16* Phh = (bf16*)alloc((size_t)192 * 32 * 512 * 2);      // Whh j-sliced frags
  bf16* WT_qobs = (bf16*)alloc((size_t)XX * HH * 2);         // q_W1[:X]^T (row-major [n][k])
  bf16* WT_p1  = (bf16*)alloc((size_t)HH * HH * 2);          // pW1^T
  bf16* WT_ph  = (bf16*)alloc((size_t)512 * HH * 2);         // [pWm|pWs]^T
  bf16* obs_preT = (bf16*)alloc((size_t)TT * HH * BB * 2);   // [t][col][row]; p_hid alias
  bf16* p_hid  = obs_preT;
  bf16* act_bf = (bf16*)alloc((size_t)TT * BB * AA * 2);
  bf16* h_bf   = (bf16*)alloc((size_t)BB * HH * 2);
  bf16* hid_q  = (bf16*)alloc((size_t)BB * HH * 2);
  bf16* z_bf   = (bf16*)alloc((size_t)BB * ZZ * 2);
  bf16* a_buf  = (bf16*)alloc((size_t)BB * HH * 2);
  unsigned* bar = (unsigned*)alloc(4096);
  (void)ws_size; (void)in_sizes; (void)n_in; (void)out_size;

  hipMemsetAsync(bar, 0, 4096, stream);

  // ---- weight packing ----
  {
    long tq1 = 64L * 32 * 64;
    pack16<<<(int)((tq1 + 255) / 256), 256, 0, stream>>>(qW1, Pq1, 1024, 1024, 32, 1024, tq1, 1, 0);
    long tih = 192L * 32 * 64;
    pack16<<<(int)((tih + 255) / 256), 256, 0, stream>>>(gWih, Pih, 3072, 0, 32, 1024, tih, 3, 1024);
    pack16<<<(int)((tih + 255) / 256), 256, 0, stream>>>(gWhh, Phh, 3072, 0, 32, 1024, tih, 3, 1024);
    long tag = 64L * 10 * 64;
    pack16<<<(int)((tag + 255) / 256), 256, 0, stream>>>(aggrW, Pag, 1024, 0, 10, 320, tag, 1, 0);
    pack_qh<<<32 * 32 * 64 / 256, 256, 0, stream>>>(qWm, qWs, Pqh);
  }
  dim3 tb(32, 8);
  transpose_cvt<<<dim3(32, 32), tb, 0, stream>>>(qW1, WT_qobs, 1024, 1024, 1024, 0);
  transpose_cvt<<<dim3(32, 32), tb, 0, stream>>>(pW1, WT_p1, 1024, 1024, 1024, 0);
  transpose_cvt<<<dim3(8, 32), tb, 0, stream>>>(pWm, WT_ph, 1024, 256, 256, 0);
  transpose_cvt<<<dim3(8, 32), tb, 0, stream>>>(pWs, WT_ph + 256 * 1024, 1024, 256, 256, 0);
  cvt_bf16<<<TT * BB * AA / 4 / 256, 256, 0, stream>>>(act, act_bf, (long)TT * BB * AA);
  init_k<<<BB * HH / 256, 256, 0, stream>>>(h_bf, dout);

  {  // obs_preT = (obs @ qW1[:X]) transposed-store  (fully parallel, M = T*B)
    GArgs a{};
    a.Af = obs; a.lda = XX; a.Bt = WT_qobs;
    a.M = TT * BB; a.N = HH; a.K = XX; a.out_bf = obs_preT;
    gemm_k<128, 128, 7, true><<<(TT * BB / 128) * (HH / 128), 256, 0, stream>>>(a);
  }

  {  // persistent scan over all 64 steps
    ScanArgs s{};
    s.Pq1 = Pq1; s.Pqh = Pqh; s.Pag = Pag; s.Pih = Pih; s.Phh = Phh;
    s.obs_preT = obs_preT; s.act_bf = act_bf;
    s.h_bf = h_bf; s.hid_q = hid_q; s.z_bf = z_bf; s.a_buf = a_buf;
    s.b_q1 = qb1; s.b_ghh = gbhh; s.b_qm = qbm; s.b_qs = qbs;
    s.b_ag = aggrB; s.b_gih = gbih;
    s.eps = eps; s.dout = dout; s.bar = bar;
    scan_k<<<NBLK, NTHR, 0, stream>>>(s);
  }

  {  // p_hid = elu(beliefs[0:T*B] @ pW1 + b1)  (batched)
    GArgs a{};
    a.Af = dout; a.lda = HH; a.Bt = WT_p1;
    a.M = TT * BB; a.N = HH; a.K = HH; a.out_bf = p_hid; a.b_p1 = pb1;
    gemm_k<128, 128, 5, true><<<(TT * BB / 128) * (HH / 128), 256, 0, stream>>>(a);
  }
  {  // p-heads: p_hid @ [pWm|pWs] -> d_out
    GArgs a{};
    a.A = p_hid; a.lda = HH; a.Bt = WT_ph;
    a.M = TT * BB; a.N = 512; a.K = HH;
    a.b_pm = pbm; a.b_ps = pbs; a.dout = dout;
    gemm_k<128, 128, 6, false><<<(TT * BB / 128) * (512 / 128), 256, 0, stream>>>(a);
  }
}

// Round 6
// 9615.586 us; speedup vs baseline: 2.1688x; 2.1688x over previous
//
#include <hip/hip_runtime.h>
#include <hip/hip_bf16.h>
#include <stdint.h>

#define TT 64
#define BB 512
#define XX 1024
#define HH 1024
#define ZZ 256
#define AA 64

#define NBLK 256
#define NTHR 512

typedef __bf16 bf16;
typedef bf16 bf16x8 __attribute__((ext_vector_type(8)));
typedef float f32x4 __attribute__((ext_vector_type(4)));

// d_out layout (fp32): beliefs[T+1,B,H] | q_loc | q_scale | p_loc | p_scale | z_q
#define SZ_BEL ((long)(TT + 1) * BB * HH)
#define SZ_TBZ ((long)TT * BB * ZZ)
#define OFF_QL (SZ_BEL)
#define OFF_QS (OFF_QL + SZ_TBZ)
#define OFF_PL (OFF_QL + 2 * SZ_TBZ)
#define OFF_PS (OFF_QL + 3 * SZ_TBZ)
#define OFF_ZQ (OFF_QL + 4 * SZ_TBZ)

#define GLL16(g, l)                                                         \
  __builtin_amdgcn_global_load_lds(                                         \
      (__attribute__((address_space(1))) void*)(g),                         \
      (__attribute__((address_space(3))) void*)(l), 16, 0, 0)

#define MFMA(a, b, c) __builtin_amdgcn_mfma_f32_16x16x32_bf16(a, b, c, 0, 0, 0)

#define ALOAD_U64(p) __hip_atomic_load((const unsigned long long*)(p), __ATOMIC_RELAXED, __HIP_MEMORY_SCOPE_AGENT)
#define ALOAD_F32(p) __hip_atomic_load((const float*)(p), __ATOMIC_RELAXED, __HIP_MEMORY_SCOPE_AGENT)
#define ALOAD_U32(p) __hip_atomic_load((const unsigned*)(p), __ATOMIC_RELAXED, __HIP_MEMORY_SCOPE_AGENT)
#define ASTORE_U16(p, v) __hip_atomic_store((unsigned short*)(p), (v), __ATOMIC_RELAXED, __HIP_MEMORY_SCOPE_AGENT)
#define ASTORE_F32(p, v) __hip_atomic_store((float*)(p), (v), __ATOMIC_RELAXED, __HIP_MEMORY_SCOPE_AGENT)
#define ASTORE_U32(p, v) __hip_atomic_store((unsigned*)(p), (v), __ATOMIC_RELAXED, __HIP_MEMORY_SCOPE_AGENT)

__device__ __forceinline__ float eluf(float x) { return x > 0.f ? x : expf(x) - 1.f; }
__device__ __forceinline__ float splusf(float x) { return fmaxf(x, 0.f) + log1pf(expf(-fabsf(x))); }
__device__ __forceinline__ float sigf(float x) { return 1.f / (1.f + expf(-x)); }
__device__ __forceinline__ unsigned short bf2u(bf16 v) { return __builtin_bit_cast(unsigned short, v); }
__device__ __forceinline__ bf16x8 ldg8(const bf16* p) { return *(const bf16x8*)p; }

// swizzled frag read from one 64x64-elem LDS k-tile (64 rows x 128B)
__device__ __forceinline__ bf16x8 ldfrag(const char* tile, int row, int w) {
  return *(const bf16x8*)(tile + row * 128 + (w ^ ((row & 7) << 4)));
}

// Stage KTILES 64x64 k-tiles (64 rows) into LDS via IF-coherent 8B atomic loads.
// Two-pass (all loads issued, then all ds_writes) for full latency overlap.
template <int KTILES>
__device__ __forceinline__ void stage_panel(const bf16* base, int ldE, char* lds) {
  unsigned long long v[2 * KTILES];
#pragma unroll
  for (int i = 0; i < 2 * KTILES; ++i) {
    int u = threadIdx.x + i * NTHR;
    int ktile = u >> 10, rem = u & 1023;
    int row = rem >> 4, cb = (rem & 15) * 8;
    v[i] = ALOAD_U64((const char*)(base + (long)row * ldE + ktile * 64) + cb);
  }
  __builtin_amdgcn_sched_barrier(0);
#pragma unroll
  for (int i = 0; i < 2 * KTILES; ++i) {
    int u = threadIdx.x + i * NTHR;
    int ktile = u >> 10, rem = u & 1023;
    int row = rem >> 4, cb = (rem & 15) * 8;
    *(unsigned long long*)(lds + ktile * 8192 + row * 128 + (cb ^ ((row & 7) << 4))) = v[i];
  }
}

__device__ __forceinline__ void stage_tile(const bf16* base, int ldE, char* ldsTile) {
  unsigned long long v[2];
#pragma unroll
  for (int i = 0; i < 2; ++i) {
    int u = threadIdx.x + i * NTHR;
    int row = u >> 4, cb = (u & 15) * 8;
    v[i] = ALOAD_U64((const char*)(base + (long)row * ldE) + cb);
  }
  __builtin_amdgcn_sched_barrier(0);
#pragma unroll
  for (int i = 0; i < 2; ++i) {
    int u = threadIdx.x + i * NTHR;
    int row = u >> 4, cb = (u & 15) * 8;
    *(unsigned long long*)(ldsTile + row * 128 + (cb ^ ((row & 7) << 4))) = v[i];
  }
}

// Group-local (32-block) barrier: per-rank arrival slots + go flag, IF-coherent,
// no fences, no RMW contention. Placement-proof (no XCD assumptions).
__device__ __forceinline__ void gbar(unsigned* arr, unsigned* go, int rank, unsigned gen) {
  __syncthreads();
  const int tid = threadIdx.x;
  if (tid == 0) ASTORE_U32(&arr[rank], gen);
  if (rank == 0) {
    if (tid < 64) {
      const int slot = tid & 31;
      while (ALOAD_U32(&arr[slot]) < gen) __builtin_amdgcn_s_sleep(2);
      if (tid == 0) ASTORE_U32(go, gen);
    }
  } else if (tid == 0) {
    while (ALOAD_U32(go) < gen) __builtin_amdgcn_s_sleep(2);
  }
  __syncthreads();
  asm volatile("" ::: "memory");
}

struct ScanArgs {
  const bf16 *Pq1, *Pqh, *Pag, *Pih, *Phh;  // frag-linear packed weights
  const bf16 *obs_preT, *act_bf;
  bf16 *h, *hid_q, *z, *a;
  float* ghf;
  const float *b_q1, *b_ghh, *b_qm, *b_qs, *b_ag, *b_gih;
  const float* eps;
  float* dout;
  unsigned *arrive, *go;  // [8][32] each
};

__global__ __launch_bounds__(NTHR, 2) void scan_k(ScanArgs s) {
  __shared__ __align__(16) char smem[131072];
  const int bid = blockIdx.x, tid = threadIdx.x;
  const int g = bid & 7, rank = bid >> 3;   // 8 groups x 32 ranks; group owns 64 rows
  const int wid = tid >> 6, lane = tid & 63;
  const int lr = lane & 15, lk = lane >> 4;
  unsigned gen = 0;
  unsigned* arr = s.arrive + g * 32;
  unsigned* go = s.go + g * 32;

  bf16* hg = s.h + (long)g * 64 * HH;
  bf16* hid_g = s.hid_q + (long)g * 64 * HH;
  bf16* z_g = s.z + (long)g * 64 * ZZ;
  bf16* a_g = s.a + (long)g * 64 * HH;
  float* gh_g = s.ghf + (long)g * 64 * 3072;

  float hreg[4] = {0.f, 0.f, 0.f, 0.f};

  for (int t = 0; t < TT; ++t) {
    // ===== P1: ranks 0-7: hid_q = elu(h@Wq1h + obs_pre + b) (128 cols each)
    //           ranks 8-31: gh = h@Whh raw fp32 (128 of 3072 cols each)
    if (rank < 8) {
      const int mh = wid & 1, nq = wid >> 1;
      const bf16* bp0 = s.Pq1 + ((long)(rank * 8 + nq * 2) * 32) * 512 + lane * 8;
      const bf16* bp1 = bp0 + (long)32 * 512;
      bf16x8 br0[4], br1[4];
#pragma unroll
      for (int p = 0; p < 4; ++p) { br0[p] = ldg8(bp0 + p * 512); br1[p] = ldg8(bp1 + p * 512); }
      const int cb = rank * 128 + nq * 32;
      unsigned long long ov[2][2];
#pragma unroll
      for (int mi = 0; mi < 2; ++mi)
#pragma unroll
        for (int nj = 0; nj < 2; ++nj)
          ov[mi][nj] = *(const unsigned long long*)&s.obs_preT[
              ((long)t * HH + cb + nj * 16 + lr) * BB + g * 64 + mh * 32 + mi * 16 + lk * 4];
      stage_panel<16>(hg, HH, smem);
      __syncthreads();
      f32x4 acc[2][2] = {};
#pragma unroll
      for (int kt = 0; kt < 32; ++kt) {
        const int sl = kt & 3;
        const char* tb = smem + (kt >> 1) * 8192;
        const int w = (kt & 1) * 64 + lk * 16;
        bf16x8 a0 = ldfrag(tb, mh * 32 + lr, w);
        bf16x8 a1 = ldfrag(tb, mh * 32 + 16 + lr, w);
        acc[0][0] = MFMA(a0, br0[sl], acc[0][0]);
        acc[1][0] = MFMA(a1, br0[sl], acc[1][0]);
        acc[0][1] = MFMA(a0, br1[sl], acc[0][1]);
        acc[1][1] = MFMA(a1, br1[sl], acc[1][1]);
        if (kt + 4 < 32) { br0[sl] = ldg8(bp0 + (kt + 4) * 512); br1[sl] = ldg8(bp1 + (kt + 4) * 512); }
      }
#pragma unroll
      for (int mi = 0; mi < 2; ++mi)
#pragma unroll
        for (int nj = 0; nj < 2; ++nj) {
          unsigned long long o8 = ov[mi][nj];
#pragma unroll
          for (int r = 0; r < 4; ++r) {
            int row = mh * 32 + mi * 16 + lk * 4 + r;
            int col = cb + nj * 16 + lr;
            float ob = (float)__builtin_bit_cast(bf16, (unsigned short)(o8 >> (16 * r)));
            float x = acc[mi][nj][r] + s.b_q1[col] + ob;
            ASTORE_U16(&hid_g[row * HH + col], bf2u((bf16)eluf(x)));
          }
        }
    } else {
      const int rb = rank - 8;
      const int mh = wid & 1, nq = wid >> 1;
      const bf16* bp0 = s.Phh + ((long)(rb * 8 + nq * 2) * 32) * 512 + lane * 8;
      const bf16* bp1 = bp0 + (long)32 * 512;
      bf16x8 br0[4], br1[4];
#pragma unroll
      for (int p = 0; p < 4; ++p) { br0[p] = ldg8(bp0 + p * 512); br1[p] = ldg8(bp1 + p * 512); }
      stage_panel<16>(hg, HH, smem);
      __syncthreads();
      f32x4 acc[2][2] = {};
#pragma unroll
      for (int kt = 0; kt < 32; ++kt) {
        const int sl = kt & 3;
        const char* tb = smem + (kt >> 1) * 8192;
        const int w = (kt & 1) * 64 + lk * 16;
        bf16x8 a0 = ldfrag(tb, mh * 32 + lr, w);
        bf16x8 a1 = ldfrag(tb, mh * 32 + 16 + lr, w);
        acc[0][0] = MFMA(a0, br0[sl], acc[0][0]);
        acc[1][0] = MFMA(a1, br0[sl], acc[1][0]);
        acc[0][1] = MFMA(a0, br1[sl], acc[0][1]);
        acc[1][1] = MFMA(a1, br1[sl], acc[1][1]);
        if (kt + 4 < 32) { br0[sl] = ldg8(bp0 + (kt + 4) * 512); br1[sl] = ldg8(bp1 + (kt + 4) * 512); }
      }
      const int cb = rb * 128 + nq * 32;
#pragma unroll
      for (int mi = 0; mi < 2; ++mi)
#pragma unroll
        for (int nj = 0; nj < 2; ++nj)
#pragma unroll
          for (int r = 0; r < 4; ++r) {
            int row = mh * 32 + mi * 16 + lk * 4 + r;
            ASTORE_F32(&gh_g[(long)row * 3072 + cb + nj * 16 + lr], acc[mi][nj][r]);
          }
    }
    gbar(arr, go, rank, ++gen);

    // ===== P2: q-heads dual (loc|scale) + rsample; rank covers 8 j-cols
    {
      stage_panel<16>(hid_g, HH, smem);
      __syncthreads();
      if (wid < 4) {
        const int mq = wid;
        const bf16* bp = s.Pqh + ((long)rank * 32) * 512 + lane * 8;
        bf16x8 br[4];
#pragma unroll
        for (int p = 0; p < 4; ++p) br[p] = ldg8(bp + p * 512);
        const int j0 = rank * 8;
        float ev[4];
#pragma unroll
        for (int r = 0; r < 4; ++r) {
          long grow = (long)g * 64 + mq * 16 + lk * 4 + r;
          ev[r] = s.eps[((long)t * BB + grow) * ZZ + j0 + (lr & 7)];
        }
        f32x4 acc = {};
#pragma unroll
        for (int kt = 0; kt < 32; ++kt) {
          const int sl = kt & 3;
          bf16x8 a = ldfrag(smem + (kt >> 1) * 8192, mq * 16 + lr, (kt & 1) * 64 + lk * 16);
          acc = MFMA(a, br[sl], acc);
          if (kt + 4 < 32) br[sl] = ldg8(bp + (kt + 4) * 512);
        }
#pragma unroll
        for (int r = 0; r < 4; ++r) {
          int row = mq * 16 + lk * 4 + r;
          long grow = (long)g * 64 + row;
          long o = ((long)t * BB + grow) * ZZ + j0 + (lr & 7);
          float myv = acc[r] + ((lr < 8) ? s.b_qm[j0 + (lr & 7)] : s.b_qs[j0 + (lr & 7)]);
          float sp = splusf(myv);
          float sc = __shfl(sp, lane + 8, 64);
          if (lr < 8) {
            float zv = myv + sc * ev[r];
            s.dout[OFF_QL + o] = myv;
            s.dout[OFF_ZQ + o] = zv;
            ASTORE_U16(&z_g[row * ZZ + j0 + lr], bf2u((bf16)zv));
          } else {
            s.dout[OFF_QS + o] = sp;
          }
        }
      }
    }
    gbar(arr, go, rank, ++gen);

    // ===== P3: a = elu([z|act]@aggrW + b); rank covers 32 cols, K=320
    {
      stage_panel<4>(z_g, ZZ, smem);
      stage_tile(s.act_bf + ((long)t * BB + (long)g * 64) * AA, AA, smem + 4 * 8192);
      __syncthreads();
      const int mq = wid & 3, nf = wid >> 2;
      const bf16* bp = s.Pag + ((long)(rank * 2 + nf) * 10) * 512 + lane * 8;
      bf16x8 br[10];
#pragma unroll
      for (int p = 0; p < 10; ++p) br[p] = ldg8(bp + (long)p * 512);
      f32x4 acc = {};
#pragma unroll
      for (int kt = 0; kt < 10; ++kt) {
        bf16x8 a = ldfrag(smem + (kt >> 1) * 8192, mq * 16 + lr, (kt & 1) * 64 + lk * 16);
        acc = MFMA(a, br[kt], acc);
      }
      const int colb = rank * 32 + nf * 16;
#pragma unroll
      for (int r = 0; r < 4; ++r) {
        int row = mq * 16 + lk * 4 + r;
        int col = colb + lr;
        ASTORE_U16(&a_g[row * HH + col], bf2u((bf16)eluf(acc[r] + s.b_ag[col])));
      }
    }
    gbar(arr, go, rank, ++gen);

    // ===== P4: gi = a@Wih (3 gates x 32 j per rank) + full GRU fuse, h in regs
    {
      const int mq = wid & 3, jf = wid >> 2;
      const int j = rank * 32 + jf * 16 + lr;
      const long F0 = (long)rank * 6 + jf;
      const bf16* bpg0 = s.Pih + ((F0 + 0) * 32) * 512 + lane * 8;
      const bf16* bpg1 = s.Pih + ((F0 + 2) * 32) * 512 + lane * 8;
      const bf16* bpg2 = s.Pih + ((F0 + 4) * 32) * 512 + lane * 8;
      bf16x8 br0[4], br1[4], br2[4];
#pragma unroll
      for (int p = 0; p < 4; ++p) {
        br0[p] = ldg8(bpg0 + p * 512); br1[p] = ldg8(bpg1 + p * 512); br2[p] = ldg8(bpg2 + p * 512);
      }
      float ghv[3][4];
#pragma unroll
      for (int r = 0; r < 4; ++r) {
        int row = mq * 16 + lk * 4 + r;
#pragma unroll
        for (int gt = 0; gt < 3; ++gt)
          ghv[gt][r] = ALOAD_F32(&gh_g[(long)row * 3072 + gt * 1024 + j]);
      }
      stage_panel<16>(a_g, HH, smem);
      __syncthreads();
      f32x4 gi0 = {}, gi1 = {}, gi2 = {};
#pragma unroll
      for (int kt = 0; kt < 32; ++kt) {
        const int sl = kt & 3;
        bf16x8 a = ldfrag(smem + (kt >> 1) * 8192, mq * 16 + lr, (kt & 1) * 64 + lk * 16);
        gi0 = MFMA(a, br0[sl], gi0);
        gi1 = MFMA(a, br1[sl], gi1);
        gi2 = MFMA(a, br2[sl], gi2);
        if (kt + 4 < 32) {
          br0[sl] = ldg8(bpg0 + (kt + 4) * 512);
          br1[sl] = ldg8(bpg1 + (kt + 4) * 512);
          br2[sl] = ldg8(bpg2 + (kt + 4) * 512);
        }
      }
      const float bi0 = s.b_gih[j], bi1 = s.b_gih[HH + j], bi2 = s.b_gih[2 * HH + j];
      const float bh0 = s.b_ghh[j], bh1 = s.b_ghh[HH + j], bh2 = s.b_ghh[2 * HH + j];
#pragma unroll
      for (int r = 0; r < 4; ++r) {
        int row = mq * 16 + lk * 4 + r;
        float rr = sigf(gi0[r] + bi0 + ghv[0][r] + bh0);
        float zz = sigf(gi1[r] + bi1 + ghv[1][r] + bh1);
        float nn = tanhf(gi2[r] + bi2 + rr * (ghv[2][r] + bh2));
        float hnew = (1.f - zz) * nn + zz * hreg[r];
        hreg[r] = hnew;
        ASTORE_U16(&hg[row * HH + j], bf2u((bf16)hnew));
        s.dout[(long)(t + 1) * BB * HH + ((long)g * 64 + row) * HH + j] = hnew;
      }
    }
    gbar(arr, go, rank, ++gen);
  }
}

// ---------------- weight packing (frag-linear) -------------------------------
// dst[((f*kts + kt)*64 + l)*8 + e] = W[(row0 + kt*32 + (l>>4)*8 + e)*ld + col]
__global__ void pack16(const float* __restrict__ W, bf16* __restrict__ dst,
                       int ld, int row0, int kts, int kmax, long total,
                       int gmod, int gstride) {
  long idx = (long)blockIdx.x * 256 + threadIdx.x;
  if (idx >= total) return;
  int l = (int)(idx & 63);
  long fk = idx >> 6;
  int kt = (int)(fk % kts);
  int f = (int)(fk / kts);
  int col = (f % gmod) * gstride + (f / gmod) * 16 + (l & 15);
  int k = kt * 32 + (l >> 4) * 8;
  bf16x8 v;
#pragma unroll
  for (int e = 0; e < 8; ++e) {
    int kk = k + e;
    v[e] = (bf16)((kk < kmax) ? W[(long)(row0 + kk) * ld + col] : 0.f);
  }
  *(bf16x8*)&dst[idx * 8] = v;
}

// Wih j-sliced: F = (js*3+gate)*2 + jf; col = gate*1024 + js*32 + jf*16 + (l&15)
__global__ void pack_ih(const float* __restrict__ W, bf16* __restrict__ dst) {
  long idx = (long)blockIdx.x * 256 + threadIdx.x;  // 192*32*64
  int l = (int)(idx & 63);
  long fk = idx >> 6;
  int kt = (int)(fk & 31);
  int F = (int)(fk >> 5);
  int jf = F & 1, gate = (F >> 1) % 3, js = F / 6;
  int col = gate * 1024 + js * 32 + jf * 16 + (l & 15);
  int k = kt * 32 + (l >> 4) * 8;
  bf16x8 v;
#pragma unroll
  for (int e = 0; e < 8; ++e) v[e] = (bf16)W[(long)(k + e) * 3072 + col];
  *(bf16x8*)&dst[idx * 8] = v;
}

// dual loc/scale frag: cols lr<8 from Wm[:, f*8..], lr>=8 from Ws[:, f*8..]
__global__ void pack_qh(const float* __restrict__ Wm, const float* __restrict__ Ws,
                        bf16* __restrict__ dst) {
  long idx = (long)blockIdx.x * 256 + threadIdx.x;  // 32*32*64
  int l = (int)(idx & 63);
  long fk = idx >> 6;
  int f = (int)(fk >> 5);
  int k = (int)((fk & 31) * 32) + (l >> 4) * 8;
  const float* W = ((l & 15) < 8) ? Wm : Ws;
  int col = f * 8 + (l & 7);
  bf16x8 v;
#pragma unroll
  for (int e = 0; e < 8; ++e) v[e] = (bf16)W[(long)(k + e) * 256 + col];
  *(bf16x8*)&dst[idx * 8] = v;
}

// ---------------- batched GEMMs (prep / tails) ----------------

struct GArgs {
  const bf16* A; const float* Af;
  long lda;
  const bf16* Bt;
  int M, N, K;
  const float *b_p1, *b_pm, *b_ps;
  bf16* out_bf;
  float* dout;
};

// EPI: 5 = elu+bias -> bf16   6 = p-heads -> d_out   7 = bf16 transposed [t][col][row]
template <int BM, int BN, int EPI, bool AF32>
__global__ __launch_bounds__(256) void gemm_k(GArgs g) {
  constexpr int BK = 32;
  constexpr int WTM = BM / 2, WTN = BN / 2;
  constexpr int MR = WTM / 16, NR = WTN / 16;
  constexpr int CA = BM * 4 / 256, CB = BN * 4 / 256;
  __shared__ bf16 sA[BM * BK];
  __shared__ bf16 sB[BN * BK];
  const int nbm = g.M / BM;
  const int bm = blockIdx.x % nbm, bn = blockIdx.x / nbm;
  const int m0 = bm * BM, n0 = bn * BN;
  const int tid = threadIdx.x;
  const int wid = tid >> 6, lane = tid & 63;
  const int wm = wid & 1, wn = wid >> 1;
  const int lr = lane & 15, lk = lane >> 4;

  f32x4 acc[MR][NR] = {};

  for (int k0 = 0; k0 < g.K; k0 += BK) {
    __syncthreads();
    if constexpr (AF32) {
#pragma unroll
      for (int i = 0; i < CA; i++) {
        int c = tid + i * 256, row = c >> 2, kc = c & 3;
        const float* sp = g.Af + (long)(m0 + row) * g.lda + k0 + kc * 8;
        float4 v0 = *(const float4*)sp;
        float4 v1 = *(const float4*)(sp + 4);
        bf16x8 p;
        p[0] = (bf16)v0.x; p[1] = (bf16)v0.y; p[2] = (bf16)v0.z; p[3] = (bf16)v0.w;
        p[4] = (bf16)v1.x; p[5] = (bf16)v1.y; p[6] = (bf16)v1.z; p[7] = (bf16)v1.w;
        *(bf16x8*)&sA[c * 8] = p;
      }
    } else {
#pragma unroll
      for (int i = 0; i < CA; i++) {
        int c = tid + i * 256, row = c >> 2, kc = c & 3;
        GLL16(g.A + (long)(m0 + row) * g.lda + k0 + kc * 8, &sA[c * 8]);
      }
    }
#pragma unroll
    for (int i = 0; i < CB; i++) {
      int c = tid + i * 256, row = c >> 2, kc = c & 3;
      GLL16(g.Bt + (long)(n0 + row) * g.K + k0 + kc * 8, &sB[c * 8]);
    }
    __syncthreads();
    bf16x8 af[MR];
#pragma unroll
    for (int mi = 0; mi < MR; mi++)
      af[mi] = *(const bf16x8*)&sA[(wm * WTM + mi * 16 + lr) * BK + lk * 8];
#pragma unroll
    for (int nj = 0; nj < NR; nj++) {
      bf16x8 bfr = *(const bf16x8*)&sB[(wn * WTN + nj * 16 + lr) * BK + lk * 8];
#pragma unroll
      for (int mi = 0; mi < MR; mi++)
        acc[mi][nj] = MFMA(af[mi], bfr, acc[mi][nj]);
    }
  }

#pragma unroll
  for (int mi = 0; mi < MR; mi++)
#pragma unroll
    for (int nj = 0; nj < NR; nj++)
#pragma unroll
      for (int r = 0; r < 4; r++) {
        const int row = m0 + wm * WTM + mi * 16 + lk * 4 + r;
        const int col = n0 + wn * WTN + nj * 16 + lr;
        float v = acc[mi][nj][r];
        if constexpr (EPI == 7) {
          g.out_bf[((long)(row >> 9) * HH + col) * BB + (row & 511)] = (bf16)v;
        } else if constexpr (EPI == 5) {
          g.out_bf[(long)row * g.N + col] = (bf16)eluf(v + g.b_p1[col]);
        } else {
          int region = col >> 8, j = col & 255;
          float x = v + (region ? g.b_ps[j] : g.b_pm[j]);
          if (region) x = splusf(x);
          g.dout[(region ? OFF_PS : OFF_PL) + (long)row * ZZ + j] = x;
        }
      }
}

// dst[n*K + k] = bf16(src[(k + k_off)*ld + n])
__global__ void transpose_cvt(const float* __restrict__ src, bf16* __restrict__ dst,
                              int K, int N, int ld, int k_off) {
  __shared__ float tile[32][33];
  const int nb = blockIdx.x * 32, kb = blockIdx.y * 32;
  const int tx = threadIdx.x, ty = threadIdx.y;
#pragma unroll
  for (int j = 0; j < 32; j += 8)
    tile[ty + j][tx] = src[(long)(kb + ty + j + k_off) * ld + nb + tx];
  __syncthreads();
#pragma unroll
  for (int j = 0; j < 32; j += 8)
    dst[(long)(nb + ty + j) * K + kb + tx] = (bf16)tile[tx][ty + j];
}

__global__ void cvt_bf16(const float* __restrict__ src, bf16* __restrict__ dst, long n) {
  long i = ((long)blockIdx.x * blockDim.x + threadIdx.x) * 4;
  if (i < n) {
    float4 v = *(const float4*)(src + i);
    dst[i] = (bf16)v.x; dst[i + 1] = (bf16)v.y;
    dst[i + 2] = (bf16)v.z; dst[i + 3] = (bf16)v.w;
  }
}

__global__ void init_k(bf16* hbf, float* dout) {
  int i = blockIdx.x * 256 + threadIdx.x;
  hbf[i] = (bf16)0.f;
  dout[i] = 0.f;  // beliefs[0] = h0 = 0
}

extern "C" void kernel_launch(void* const* d_in, const int* in_sizes, int n_in,
                              void* d_out, int out_size, void* d_ws, size_t ws_size,
                              hipStream_t stream) {
  const float* obs  = (const float*)d_in[0];
  const float* act  = (const float*)d_in[1];
  const float* eps  = (const float*)d_in[2];
  const float* aggrW = (const float*)d_in[3];
  const float* aggrB = (const float*)d_in[4];
  const float* gWih = (const float*)d_in[5];
  const float* gWhh = (const float*)d_in[6];
  const float* gbih = (const float*)d_in[7];
  const float* gbhh = (const float*)d_in[8];
  const float* qW1  = (const float*)d_in[9];
  const float* qb1  = (const float*)d_in[10];
  const float* qWm  = (const float*)d_in[11];
  const float* qbm  = (const float*)d_in[12];
  const float* qWs  = (const float*)d_in[13];
  const float* qbs  = (const float*)d_in[14];
  const float* pW1  = (const float*)d_in[15];
  const float* pb1  = (const float*)d_in[16];
  const float* pWm  = (const float*)d_in[17];
  const float* pbm  = (const float*)d_in[18];
  const float* pWs  = (const float*)d_in[19];
  const float* pbs  = (const float*)d_in[20];
  float* dout = (float*)d_out;

  char* w = (char*)d_ws;
  size_t off = 0;
  auto alloc = [&](size_t bytes) -> char* {
    char* r = w + off;
    off = (off + bytes + 255) & ~(size_t)255;
    return r;
  };
  bf16* Pq1 = (bf16*)alloc((size_t)64 * 32 * 512 * 2);
  bf16* Pqh = (bf16*)alloc((size_t)32 * 32 * 512 * 2);
  bf16* Pag = (bf16*)alloc((size_t)64 * 10 * 512 * 2);
  bf16* Pih = (bf16*)alloc((size_t)192 * 32 * 512 * 2);
  bf16* Phh = (bf16*)alloc((size_t)192 * 32 * 512 * 2);
  bf16* WT_qobs = (bf16*)alloc((size_t)XX * HH * 2);
  bf16* WT_p1  = (bf16*)alloc((size_t)HH * HH * 2);
  bf16* WT_ph  = (bf16*)alloc((size_t)512 * HH * 2);
  bf16* obs_preT = (bf16*)alloc((size_t)TT * HH * BB * 2);  // p_hid alias after scan
  bf16* p_hid  = obs_preT;
  bf16* act_bf = (bf16*)alloc((size_t)TT * BB * AA * 2);
  bf16* h_bf   = (bf16*)alloc((size_t)BB * HH * 2);
  bf16* hid_q  = (bf16*)alloc((size_t)BB * HH * 2);
  bf16* z_bf   = (bf16*)alloc((size_t)BB * ZZ * 2);
  bf16* a_buf  = (bf16*)alloc((size_t)BB * HH * 2);
  float* ghf   = (float*)alloc((size_t)BB * 3 * HH * 4);
  unsigned* bar = (unsigned*)alloc(4096);
  (void)ws_size; (void)in_sizes; (void)n_in; (void)out_size;

  hipMemsetAsync(bar, 0, 4096, stream);

  pack16<<<512, 256, 0, stream>>>(qW1, Pq1, 1024, 1024, 32, 1024, 64L * 32 * 64, 1, 0);
  pack16<<<1536, 256, 0, stream>>>(gWhh, Phh, 3072, 0, 32, 1024, 192L * 32 * 64, 1, 0);
  pack_ih<<<1536, 256, 0, stream>>>(gWih, Pih);
  pack16<<<160, 256, 0, stream>>>(aggrW, Pag, 1024, 0, 10, 320, 64L * 10 * 64, 1, 0);
  pack_qh<<<256, 256, 0, stream>>>(qWm, qWs, Pqh);

  dim3 tb(32, 8);
  transpose_cvt<<<dim3(32, 32), tb, 0, stream>>>(qW1, WT_qobs, 1024, 1024, 1024, 0);
  transpose_cvt<<<dim3(32, 32), tb, 0, stream>>>(pW1, WT_p1, 1024, 1024, 1024, 0);
  transpose_cvt<<<dim3(8, 32), tb, 0, stream>>>(pWm, WT_ph, 1024, 256, 256, 0);
  transpose_cvt<<<dim3(8, 32), tb, 0, stream>>>(pWs, WT_ph + 256 * 1024, 1024, 256, 256, 0);
  cvt_bf16<<<TT * BB * AA / 4 / 256, 256, 0, stream>>>(act, act_bf, (long)TT * BB * AA);
  init_k<<<BB * HH / 256, 256, 0, stream>>>(h_bf, dout);

  {  // obs_preT = (obs @ qW1[:X]) transposed-store
    GArgs a{};
    a.Af = obs; a.lda = XX; a.Bt = WT_qobs;
    a.M = TT * BB; a.N = HH; a.K = XX; a.out_bf = obs_preT;
    gemm_k<128, 128, 7, true><<<(TT * BB / 128) * (HH / 128), 256, 0, stream>>>(a);
  }

  {  // persistent scan: 8 independent 32-block groups, group-local barriers only
    ScanArgs s{};
    s.Pq1 = Pq1; s.Pqh = Pqh; s.Pag = Pag; s.Pih = Pih; s.Phh = Phh;
    s.obs_preT = obs_preT; s.act_bf = act_bf;
    s.h = h_bf; s.hid_q = hid_q; s.z = z_bf; s.a = a_buf; s.ghf = ghf;
    s.b_q1 = qb1; s.b_ghh = gbhh; s.b_qm = qbm; s.b_qs = qbs;
    s.b_ag = aggrB; s.b_gih = gbih;
    s.eps = eps; s.dout = dout;
    s.arrive = bar; s.go = bar + 256;
    scan_k<<<NBLK, NTHR, 0, stream>>>(s);
  }

  {  // p_hid = elu(beliefs[0:T*B] @ pW1 + b1)
    GArgs a{};
    a.Af = dout; a.lda = HH; a.Bt = WT_p1;
    a.M = TT * BB; a.N = HH; a.K = HH; a.out_bf = p_hid; a.b_p1 = pb1;
    gemm_k<128, 128, 5, true><<<(TT * BB / 128) * (HH / 128), 256, 0, stream>>>(a);
  }
  {  // p-heads
    GArgs a{};
    a.A = p_hid; a.lda = HH; a.Bt = WT_ph;
    a.M = TT * BB; a.N = 512; a.K = HH;
    a.b_pm = pbm; a.b_ps = pbs; a.dout = dout;
    gemm_k<128, 128, 6, false><<<(TT * BB / 128) * (512 / 128), 256, 0, stream>>>(a);
  }
}

// Round 7
// 8273.745 us; speedup vs baseline: 2.5206x; 1.1622x over previous
//
#include <hip/hip_runtime.h>
#include <hip/hip_bf16.h>
#include <stdint.h>

#define TT 64
#define BB 512
#define XX 1024
#define HH 1024
#define ZZ 256
#define AA 64

#define NBLK 256
#define NTHR 512
#define ROWS 16      // rows per group
#define RPG 8        // ranks (blocks) per group; rank = bid & 7 -> XCD-aligned weights

typedef __bf16 bf16;
typedef bf16 bf16x8 __attribute__((ext_vector_type(8)));
typedef float f32x4 __attribute__((ext_vector_type(4)));
typedef unsigned int u32x4 __attribute__((ext_vector_type(4)));

// d_out layout (fp32): beliefs[T+1,B,H] | q_loc | q_scale | p_loc | p_scale | z_q
#define SZ_BEL ((long)(TT + 1) * BB * HH)
#define SZ_TBZ ((long)TT * BB * ZZ)
#define OFF_QL (SZ_BEL)
#define OFF_QS (OFF_QL + SZ_TBZ)
#define OFF_PL (OFF_QL + 2 * SZ_TBZ)
#define OFF_PS (OFF_QL + 3 * SZ_TBZ)
#define OFF_ZQ (OFF_QL + 4 * SZ_TBZ)

#define GLL16(g, l)                                                         \
  __builtin_amdgcn_global_load_lds(                                         \
      (__attribute__((address_space(1))) void*)(g),                         \
      (__attribute__((address_space(3))) void*)(l), 16, 0, 0)

#define MFMA(a, b, c) __builtin_amdgcn_mfma_f32_16x16x32_bf16(a, b, c, 0, 0, 0)

#define ALOAD_U64(p) __hip_atomic_load((const unsigned long long*)(p), __ATOMIC_RELAXED, __HIP_MEMORY_SCOPE_AGENT)
#define ALOAD_U32(p) __hip_atomic_load((const unsigned*)(p), __ATOMIC_RELAXED, __HIP_MEMORY_SCOPE_AGENT)
#define ASTORE_U16(p, v) __hip_atomic_store((unsigned short*)(p), (v), __ATOMIC_RELAXED, __HIP_MEMORY_SCOPE_AGENT)
#define ASTORE_U64(p, v) __hip_atomic_store((unsigned long long*)(p), (v), __ATOMIC_RELAXED, __HIP_MEMORY_SCOPE_AGENT)
#define ASTORE_U32(p, v) __hip_atomic_store((unsigned*)(p), (v), __ATOMIC_RELAXED, __HIP_MEMORY_SCOPE_AGENT)

__device__ __forceinline__ float eluf(float x) { return x > 0.f ? x : expf(x) - 1.f; }
__device__ __forceinline__ float splusf(float x) { return fmaxf(x, 0.f) + log1pf(expf(-fabsf(x))); }
__device__ __forceinline__ float sigf(float x) { return 1.f / (1.f + expf(-x)); }
__device__ __forceinline__ unsigned short bf2u(bf16 v) { return __builtin_bit_cast(unsigned short, v); }
__device__ __forceinline__ float u2f(unsigned short u) { return (float)__builtin_bit_cast(bf16, u); }
__device__ __forceinline__ bf16x8 ldg8(const bf16* p) { return *(const bf16x8*)p; }

// 16B device-coherent (L1/L2-bypass) load
__device__ __forceinline__ void cload16(u32x4& v, const void* p) {
  asm volatile("global_load_dwordx4 %0, %1, off sc0 sc1" : "=v"(v) : "v"(p));
}

// swizzled frag read from a 16-row x 64-col LDS k-tile (2KB, row stride 128B)
__device__ __forceinline__ bf16x8 ldfrag(const char* tile, int row, int w) {
  return *(const bf16x8*)(tile + row * 128 + (w ^ ((row & 7) << 4)));
}

// Stage a 16 x C bf16 row-major panel into LDS as C/64 swizzled 2KB tiles,
// via coherent 16B loads (two-pass: issue all, waitcnt, write all).
template <int C>  // C in {1024, 256}
__device__ __forceinline__ void stage_panel16(const bf16* base, char* lds) {
  constexpr int ITER = (2 * C) / NTHR;  // 16B units / threads
  u32x4 v[ITER];
#pragma unroll
  for (int i = 0; i < ITER; ++i) {
    int u = threadIdx.x + i * NTHR;
    int ktile = u >> 7, rem = u & 127;
    int row = rem >> 3, cb = (rem & 7) * 16;
    cload16(v[i], (const char*)base + (long)row * (C * 2) + ktile * 128 + cb);
  }
  asm volatile("s_waitcnt vmcnt(0)" ::: "memory");
  __builtin_amdgcn_sched_barrier(0);
#pragma unroll
  for (int i = 0; i < ITER; ++i) {
    int u = threadIdx.x + i * NTHR;
    int ktile = u >> 7, rem = u & 127;
    int row = rem >> 3, cb = (rem & 7) * 16;
    *(u32x4*)(lds + ktile * 2048 + row * 128 + (cb ^ ((row & 7) << 4))) = v[i];
  }
}

// act tile (16 x 64, read-only input): normal cached loads
__device__ __forceinline__ void stage_act(const bf16* base, char* lds) {
  if (threadIdx.x < 128) {
    int u = threadIdx.x;
    int row = u >> 3, cb = (u & 7) * 16;
    u32x4 v = *(const u32x4*)((const char*)base + row * 128 + cb);
    *(u32x4*)(lds + row * 128 + (cb ^ ((row & 7) << 4))) = v;
  }
}

// Group-local (8-rank) barrier: per-rank arrival words (one line/group) + go.
__device__ __forceinline__ void gbar(unsigned* arr, unsigned* go, int rank, unsigned gen) {
  __syncthreads();
  if (rank == 0) {
    if (threadIdx.x > 0 && threadIdx.x < RPG) {
      while (ALOAD_U32(&arr[threadIdx.x]) < gen) __builtin_amdgcn_s_sleep(2);
    }
    if (threadIdx.x == 0) ASTORE_U32(go, gen);
  } else if (threadIdx.x == 0) {
    ASTORE_U32(&arr[rank], gen);
    while (ALOAD_U32(go) < gen) __builtin_amdgcn_s_sleep(2);
  }
  __syncthreads();
  asm volatile("" ::: "memory");
}

struct ScanArgs {
  const bf16 *Pq1, *Pqh, *Pag, *Pih, *Phh;  // frag-linear packed weights
  const bf16 *obs_preT, *act_bf;
  bf16 *h, *hid, *z, *a, *ghT;
  const float *b_q1, *b_ghh, *b_qm, *b_qs, *b_ag, *b_gih;
  const float* eps;
  float* dout;
  unsigned* bar;
};

__global__ __launch_bounds__(NTHR, 2) void scan_k(ScanArgs s) {
  __shared__ __align__(16) char smem[32768];
  const int bid = blockIdx.x, tid = threadIdx.x;
  const int g = bid >> 3, rank = bid & 7;  // 32 groups x 8 ranks; rank~XCD
  const int wid = tid >> 6, lane = tid & 63;
  const int lr = lane & 15, lk = lane >> 4;
  unsigned gen = 0;
  unsigned* arr = s.bar + g * 32;
  unsigned* go = s.bar + 1024 + g * 32;

  bf16* hg = s.h + (long)g * ROWS * HH;
  bf16* hid_g = s.hid + (long)g * ROWS * HH;
  bf16* zg = s.z + (long)g * ROWS * ZZ;
  bf16* ag = s.a + (long)g * ROWS * HH;
  bf16* ghT_g = s.ghT + (long)g * 3072 * ROWS;

  float hreg[4] = {0.f, 0.f, 0.f, 0.f};

  for (int t = 0; t < TT; ++t) {
    // ===== P1: ranks 0-1: hid = elu(h@Wq1h + obs + b) (512 cols each)
    //           ranks 2-7: ghT = bf16(h@Whh)           (512 cols each)
    {
      stage_panel16<1024>(hg, smem);
      __syncthreads();
      const bool isHid = rank < 2;
      const int fb = (isHid ? rank : rank - 2) * 32 + wid * 4;
      const bf16* P = isHid ? s.Pq1 : s.Phh;
      const bf16* bp[4];
#pragma unroll
      for (int nj = 0; nj < 4; ++nj) bp[nj] = P + ((long)(fb + nj) * 32) * 512 + lane * 8;
      bf16x8 br[2][4];
#pragma unroll
      for (int nj = 0; nj < 4; ++nj) { br[0][nj] = ldg8(bp[nj]); br[1][nj] = ldg8(bp[nj] + 512); }
      f32x4 acc[4] = {};
#pragma unroll
      for (int kk = 0; kk < 32; ++kk) {
        const int sl = kk & 1;
        bf16x8 a = ldfrag(smem + (kk >> 1) * 2048, lr, (kk & 1) * 64 + lk * 16);
#pragma unroll
        for (int nj = 0; nj < 4; ++nj) acc[nj] = MFMA(a, br[sl][nj], acc[nj]);
        if (kk + 2 < 32) {
#pragma unroll
          for (int nj = 0; nj < 4; ++nj) br[sl][nj] = ldg8(bp[nj] + (kk + 2) * 512);
        }
      }
      if (isHid) {
        const int colb = rank * 512 + wid * 64;
#pragma unroll
        for (int nj = 0; nj < 4; ++nj) {
          const int col = colb + nj * 16 + lr;
          const float bq = s.b_q1[col];
          unsigned long long o8 = *(const unsigned long long*)
              &s.obs_preT[((long)t * HH + col) * BB + g * ROWS + lk * 4];
#pragma unroll
          for (int r = 0; r < 4; ++r) {
            float x = acc[nj][r] + bq + u2f((unsigned short)(o8 >> (16 * r)));
            ASTORE_U16(&hid_g[(lk * 4 + r) * HH + col], bf2u((bf16)eluf(x)));
          }
        }
      } else {
        const int colb = (rank - 2) * 512 + wid * 64;
#pragma unroll
        for (int nj = 0; nj < 4; ++nj) {
          const int cg = colb + nj * 16 + lr;
          unsigned long long pk = 0;
#pragma unroll
          for (int r = 0; r < 4; ++r)
            pk |= (unsigned long long)bf2u((bf16)acc[nj][r]) << (16 * r);
          ASTORE_U64(&ghT_g[(long)cg * ROWS + lk * 4], pk);
        }
      }
    }
    gbar(arr, go, rank, ++gen);

    // ===== P2: q-heads dual (loc|scale) + rsample; rank covers 32 j, 4 waves
    {
      stage_panel16<1024>(hid_g, smem);
      __syncthreads();
      if (wid < 4) {
        const int f = rank * 4 + wid;
        const bf16* bp = s.Pqh + ((long)f * 32) * 512 + lane * 8;
        bf16x8 br[4];
#pragma unroll
        for (int p = 0; p < 4; ++p) br[p] = ldg8(bp + p * 512);
        f32x4 acc = {};
#pragma unroll
        for (int kk = 0; kk < 32; ++kk) {
          bf16x8 a = ldfrag(smem + (kk >> 1) * 2048, lr, (kk & 1) * 64 + lk * 16);
          acc = MFMA(a, br[kk & 3], acc);
          if (kk + 4 < 32) br[kk & 3] = ldg8(bp + (kk + 4) * 512);
        }
        const int j0 = rank * 32 + wid * 8;
        const int jj = j0 + (lr & 7);
        const float bias = (lr < 8) ? s.b_qm[jj] : s.b_qs[jj];
#pragma unroll
        for (int r = 0; r < 4; ++r) {
          const int rl = lk * 4 + r;
          const long grow = (long)g * ROWS + rl;
          const long o = ((long)t * BB + grow) * ZZ + jj;
          float myv = acc[r] + bias;
          float sp = splusf(myv);
          float sc = __shfl(sp, lane + 8, 64);
          if (lr < 8) {
            float zv = myv + sc * s.eps[o];
            s.dout[OFF_QL + o] = myv;
            s.dout[OFF_ZQ + o] = zv;
            ASTORE_U16(&zg[rl * ZZ + jj], bf2u((bf16)zv));
          } else {
            s.dout[OFF_QS + o] = sp;
          }
        }
      }
    }
    gbar(arr, go, rank, ++gen);

    // ===== P3: a = elu([z|act]@aggrW + b); rank covers 128 cols, K=320
    {
      stage_panel16<256>(zg, smem);
      stage_act(s.act_bf + ((long)t * BB + (long)g * ROWS) * AA, smem + 4 * 2048);
      __syncthreads();
      const int f = rank * 8 + wid;
      const bf16* bp = s.Pag + ((long)f * 10) * 512 + lane * 8;
      bf16x8 br[10];
#pragma unroll
      for (int p = 0; p < 10; ++p) br[p] = ldg8(bp + (long)p * 512);
      f32x4 acc = {};
#pragma unroll
      for (int kk = 0; kk < 10; ++kk) {
        bf16x8 a = ldfrag(smem + (kk >> 1) * 2048, lr, (kk & 1) * 64 + lk * 16);
        acc = MFMA(a, br[kk], acc);
      }
      const int col = rank * 128 + wid * 16 + lr;
      const float ba = s.b_ag[col];
#pragma unroll
      for (int r = 0; r < 4; ++r)
        ASTORE_U16(&ag[(lk * 4 + r) * HH + col], bf2u((bf16)eluf(acc[r] + ba)));
    }
    gbar(arr, go, rank, ++gen);

    // ===== P4: gi = a@Wih (3 gates x 16 j per wave) + GRU fuse; h in regs
    {
      const int j = rank * 128 + wid * 16 + lr;
      unsigned long long ghp0 = ALOAD_U64(&ghT_g[(long)(0 * HH + j) * ROWS + lk * 4]);
      unsigned long long ghp1 = ALOAD_U64(&ghT_g[(long)(1 * HH + j) * ROWS + lk * 4]);
      unsigned long long ghp2 = ALOAD_U64(&ghT_g[(long)(2 * HH + j) * ROWS + lk * 4]);
      stage_panel16<1024>(ag, smem);
      __syncthreads();
      const int fb = rank * 8 + wid;
      const bf16* bp0 = s.Pih + ((long)(0 * 64 + fb) * 32) * 512 + lane * 8;
      const bf16* bp1 = s.Pih + ((long)(1 * 64 + fb) * 32) * 512 + lane * 8;
      const bf16* bp2 = s.Pih + ((long)(2 * 64 + fb) * 32) * 512 + lane * 8;
      bf16x8 b0[2], b1[2], b2[2];
      b0[0] = ldg8(bp0); b0[1] = ldg8(bp0 + 512);
      b1[0] = ldg8(bp1); b1[1] = ldg8(bp1 + 512);
      b2[0] = ldg8(bp2); b2[1] = ldg8(bp2 + 512);
      f32x4 gi0 = {}, gi1 = {}, gi2 = {};
#pragma unroll
      for (int kk = 0; kk < 32; ++kk) {
        const int sl = kk & 1;
        bf16x8 a = ldfrag(smem + (kk >> 1) * 2048, lr, (kk & 1) * 64 + lk * 16);
        gi0 = MFMA(a, b0[sl], gi0);
        gi1 = MFMA(a, b1[sl], gi1);
        gi2 = MFMA(a, b2[sl], gi2);
        if (kk + 2 < 32) {
          b0[sl] = ldg8(bp0 + (kk + 2) * 512);
          b1[sl] = ldg8(bp1 + (kk + 2) * 512);
          b2[sl] = ldg8(bp2 + (kk + 2) * 512);
        }
      }
      const float bi0 = s.b_gih[j], bi1 = s.b_gih[HH + j], bi2 = s.b_gih[2 * HH + j];
      const float bh0 = s.b_ghh[j], bh1 = s.b_ghh[HH + j], bh2 = s.b_ghh[2 * HH + j];
#pragma unroll
      for (int r = 0; r < 4; ++r) {
        const int rl = lk * 4 + r;
        float rr = sigf(gi0[r] + bi0 + u2f((unsigned short)(ghp0 >> (16 * r))) + bh0);
        float zz = sigf(gi1[r] + bi1 + u2f((unsigned short)(ghp1 >> (16 * r))) + bh1);
        float nn = tanhf(gi2[r] + bi2 + rr * (u2f((unsigned short)(ghp2 >> (16 * r))) + bh2));
        float hnew = (1.f - zz) * nn + zz * hreg[r];
        hreg[r] = hnew;
        ASTORE_U16(&hg[rl * HH + j], bf2u((bf16)hnew));
        s.dout[(long)(t + 1) * BB * HH + ((long)g * ROWS + rl) * HH + j] = hnew;
      }
    }
    gbar(arr, go, rank, ++gen);
  }
}

// ---------------- weight packing (frag-linear) -------------------------------
// dst[((f*kts + kt)*64 + l)*8 + e] = W[(row0 + kt*32 + (l>>4)*8 + e)*ld + col],
// col = f*16 + (l&15)
__global__ void pack16(const float* __restrict__ W, bf16* __restrict__ dst,
                       int ld, int row0, int kts, int kmax, long total) {
  long idx = (long)blockIdx.x * 256 + threadIdx.x;
  if (idx >= total) return;
  int l = (int)(idx & 63);
  long fk = idx >> 6;
  int kt = (int)(fk % kts);
  int f = (int)(fk / kts);
  int col = f * 16 + (l & 15);
  int k = kt * 32 + (l >> 4) * 8;
  bf16x8 v;
#pragma unroll
  for (int e = 0; e < 8; ++e) {
    int kk = k + e;
    v[e] = (bf16)((kk < kmax) ? W[(long)(row0 + kk) * ld + col] : 0.f);
  }
  *(bf16x8*)&dst[idx * 8] = v;
}

// dual loc/scale frag: cols lr<8 from Wm[:, f*8..], lr>=8 from Ws[:, f*8..]
__global__ void pack_qh(const float* __restrict__ Wm, const float* __restrict__ Ws,
                        bf16* __restrict__ dst) {
  long idx = (long)blockIdx.x * 256 + threadIdx.x;  // 32*32*64
  int l = (int)(idx & 63);
  long fk = idx >> 6;
  int f = (int)(fk >> 5);
  int k = (int)((fk & 31) * 32) + (l >> 4) * 8;
  const float* W = ((l & 15) < 8) ? Wm : Ws;
  int col = f * 8 + (l & 7);
  bf16x8 v;
#pragma unroll
  for (int e = 0; e < 8; ++e) v[e] = (bf16)W[(long)(k + e) * 256 + col];
  *(bf16x8*)&dst[idx * 8] = v;
}

// ---------------- batched GEMMs (prep / tails) ----------------

struct GArgs {
  const bf16* A; const float* Af;
  long lda;
  const bf16* Bt;
  int M, N, K;
  const float *b_p1, *b_pm, *b_ps;
  bf16* out_bf;
  float* dout;
};

// EPI: 5 = elu+bias -> bf16   6 = p-heads -> d_out   7 = bf16 transposed [t][col][row]
template <int BM, int BN, int EPI, bool AF32>
__global__ __launch_bounds__(256) void gemm_k(GArgs g) {
  constexpr int BK = 32;
  constexpr int WTM = BM / 2, WTN = BN / 2;
  constexpr int MR = WTM / 16, NR = WTN / 16;
  constexpr int CA = BM * 4 / 256, CB = BN * 4 / 256;
  __shared__ bf16 sA[BM * BK];
  __shared__ bf16 sB[BN * BK];
  const int nbm = g.M / BM;
  const int bm = blockIdx.x % nbm, bn = blockIdx.x / nbm;
  const int m0 = bm * BM, n0 = bn * BN;
  const int tid = threadIdx.x;
  const int wid = tid >> 6, lane = tid & 63;
  const int wm = wid & 1, wn = wid >> 1;
  const int lr = lane & 15, lk = lane >> 4;

  f32x4 acc[MR][NR] = {};

  for (int k0 = 0; k0 < g.K; k0 += BK) {
    __syncthreads();
    if constexpr (AF32) {
#pragma unroll
      for (int i = 0; i < CA; i++) {
        int c = tid + i * 256, row = c >> 2, kc = c & 3;
        const float* sp = g.Af + (long)(m0 + row) * g.lda + k0 + kc * 8;
        float4 v0 = *(const float4*)sp;
        float4 v1 = *(const float4*)(sp + 4);
        bf16x8 p;
        p[0] = (bf16)v0.x; p[1] = (bf16)v0.y; p[2] = (bf16)v0.z; p[3] = (bf16)v0.w;
        p[4] = (bf16)v1.x; p[5] = (bf16)v1.y; p[6] = (bf16)v1.z; p[7] = (bf16)v1.w;
        *(bf16x8*)&sA[c * 8] = p;
      }
    } else {
#pragma unroll
      for (int i = 0; i < CA; i++) {
        int c = tid + i * 256, row = c >> 2, kc = c & 3;
        GLL16(g.A + (long)(m0 + row) * g.lda + k0 + kc * 8, &sA[c * 8]);
      }
    }
#pragma unroll
    for (int i = 0; i < CB; i++) {
      int c = tid + i * 256, row = c >> 2, kc = c & 3;
      GLL16(g.Bt + (long)(n0 + row) * g.K + k0 + kc * 8, &sB[c * 8]);
    }
    __syncthreads();
    bf16x8 af[MR];
#pragma unroll
    for (int mi = 0; mi < MR; mi++)
      af[mi] = *(const bf16x8*)&sA[(wm * WTM + mi * 16 + lr) * BK + lk * 8];
#pragma unroll
    for (int nj = 0; nj < NR; nj++) {
      bf16x8 bfr = *(const bf16x8*)&sB[(wn * WTN + nj * 16 + lr) * BK + lk * 8];
#pragma unroll
      for (int mi = 0; mi < MR; mi++)
        acc[mi][nj] = MFMA(af[mi], bfr, acc[mi][nj]);
    }
  }

#pragma unroll
  for (int mi = 0; mi < MR; mi++)
#pragma unroll
    for (int nj = 0; nj < NR; nj++)
#pragma unroll
      for (int r = 0; r < 4; r++) {
        const int row = m0 + wm * WTM + mi * 16 + lk * 4 + r;
        const int col = n0 + wn * WTN + nj * 16 + lr;
        float v = acc[mi][nj][r];
        if constexpr (EPI == 7) {
          g.out_bf[((long)(row >> 9) * HH + col) * BB + (row & 511)] = (bf16)v;
        } else if constexpr (EPI == 5) {
          g.out_bf[(long)row * g.N + col] = (bf16)eluf(v + g.b_p1[col]);
        } else {
          int region = col >> 8, j = col & 255;
          float x = v + (region ? g.b_ps[j] : g.b_pm[j]);
          if (region) x = splusf(x);
          g.dout[(region ? OFF_PS : OFF_PL) + (long)row * ZZ + j] = x;
        }
      }
}

// dst[n*K + k] = bf16(src[(k + k_off)*ld + n])
__global__ void transpose_cvt(const float* __restrict__ src, bf16* __restrict__ dst,
                              int K, int N, int ld, int k_off) {
  __shared__ float tile[32][33];
  const int nb = blockIdx.x * 32, kb = blockIdx.y * 32;
  const int tx = threadIdx.x, ty = threadIdx.y;
#pragma unroll
  for (int j = 0; j < 32; j += 8)
    tile[ty + j][tx] = src[(long)(kb + ty + j + k_off) * ld + nb + tx];
  __syncthreads();
#pragma unroll
  for (int j = 0; j < 32; j += 8)
    dst[(long)(nb + ty + j) * K + kb + tx] = (bf16)tile[tx][ty + j];
}

__global__ void cvt_bf16(const float* __restrict__ src, bf16* __restrict__ dst, long n) {
  long i = ((long)blockIdx.x * blockDim.x + threadIdx.x) * 4;
  if (i < n) {
    float4 v = *(const float4*)(src + i);
    dst[i] = (bf16)v.x; dst[i + 1] = (bf16)v.y;
    dst[i + 2] = (bf16)v.z; dst[i + 3] = (bf16)v.w;
  }
}

__global__ void init_k(bf16* hbf, float* dout) {
  int i = blockIdx.x * 256 + threadIdx.x;
  hbf[i] = (bf16)0.f;
  dout[i] = 0.f;  // beliefs[0] = h0 = 0
}

extern "C" void kernel_launch(void* const* d_in, const int* in_sizes, int n_in,
                              void* d_out, int out_size, void* d_ws, size_t ws_size,
                              hipStream_t stream) {
  const float* obs  = (const float*)d_in[0];
  const float* act  = (const float*)d_in[1];
  const float* eps  = (const float*)d_in[2];
  const float* aggrW = (const float*)d_in[3];
  const float* aggrB = (const float*)d_in[4];
  const float* gWih = (const float*)d_in[5];
  const float* gWhh = (const float*)d_in[6];
  const float* gbih = (const float*)d_in[7];
  const float* gbhh = (const float*)d_in[8];
  const float* qW1  = (const float*)d_in[9];
  const float* qb1  = (const float*)d_in[10];
  const float* qWm  = (const float*)d_in[11];
  const float* qbm  = (const float*)d_in[12];
  const float* qWs  = (const float*)d_in[13];
  const float* qbs  = (const float*)d_in[14];
  const float* pW1  = (const float*)d_in[15];
  const float* pb1  = (const float*)d_in[16];
  const float* pWm  = (const float*)d_in[17];
  const float* pbm  = (const float*)d_in[18];
  const float* pWs  = (const float*)d_in[19];
  const float* pbs  = (const float*)d_in[20];
  float* dout = (float*)d_out;

  char* w = (char*)d_ws;
  size_t off = 0;
  auto alloc = [&](size_t bytes) -> char* {
    char* r = w + off;
    off = (off + bytes + 255) & ~(size_t)255;
    return r;
  };
  bf16* Pq1 = (bf16*)alloc((size_t)64 * 32 * 512 * 2);
  bf16* Pqh = (bf16*)alloc((size_t)32 * 32 * 512 * 2);
  bf16* Pag = (bf16*)alloc((size_t)64 * 10 * 512 * 2);
  bf16* Pih = (bf16*)alloc((size_t)192 * 32 * 512 * 2);
  bf16* Phh = (bf16*)alloc((size_t)192 * 32 * 512 * 2);
  bf16* WT_qobs = (bf16*)alloc((size_t)XX * HH * 2);
  bf16* WT_p1  = (bf16*)alloc((size_t)HH * HH * 2);
  bf16* WT_ph  = (bf16*)alloc((size_t)512 * HH * 2);
  bf16* obs_preT = (bf16*)alloc((size_t)TT * HH * BB * 2);  // p_hid alias after scan
  bf16* p_hid  = obs_preT;
  bf16* act_bf = (bf16*)alloc((size_t)TT * BB * AA * 2);
  bf16* h_bf   = (bf16*)alloc((size_t)BB * HH * 2);
  bf16* hid_q  = (bf16*)alloc((size_t)BB * HH * 2);
  bf16* z_bf   = (bf16*)alloc((size_t)BB * ZZ * 2);
  bf16* a_buf  = (bf16*)alloc((size_t)BB * HH * 2);
  bf16* ghT    = (bf16*)alloc((size_t)BB * 3 * HH * 2);  // [g][3072][16] bf16
  unsigned* bar = (unsigned*)alloc(8192);
  (void)ws_size; (void)in_sizes; (void)n_in; (void)out_size;

  hipMemsetAsync(bar, 0, 8192, stream);

  pack16<<<512, 256, 0, stream>>>(qW1, Pq1, 1024, 1024, 32, 1024, 64L * 32 * 64);
  pack16<<<1536, 256, 0, stream>>>(gWhh, Phh, 3072, 0, 32, 1024, 192L * 32 * 64);
  pack16<<<1536, 256, 0, stream>>>(gWih, Pih, 3072, 0, 32, 1024, 192L * 32 * 64);
  pack16<<<160, 256, 0, stream>>>(aggrW, Pag, 1024, 0, 10, 320, 64L * 10 * 64);
  pack_qh<<<256, 256, 0, stream>>>(qWm, qWs, Pqh);

  dim3 tb(32, 8);
  transpose_cvt<<<dim3(32, 32), tb, 0, stream>>>(qW1, WT_qobs, 1024, 1024, 1024, 0);
  transpose_cvt<<<dim3(32, 32), tb, 0, stream>>>(pW1, WT_p1, 1024, 1024, 1024, 0);
  transpose_cvt<<<dim3(8, 32), tb, 0, stream>>>(pWm, WT_ph, 1024, 256, 256, 0);
  transpose_cvt<<<dim3(8, 32), tb, 0, stream>>>(pWs, WT_ph + 256 * 1024, 1024, 256, 256, 0);
  cvt_bf16<<<TT * BB * AA / 4 / 256, 256, 0, stream>>>(act, act_bf, (long)TT * BB * AA);
  init_k<<<BB * HH / 256, 256, 0, stream>>>(h_bf, dout);

  {  // obs_preT = (obs @ qW1[:X]) transposed-store
    GArgs a{};
    a.Af = obs; a.lda = XX; a.Bt = WT_qobs;
    a.M = TT * BB; a.N = HH; a.K = XX; a.out_bf = obs_preT;
    gemm_k<128, 128, 7, true><<<(TT * BB / 128) * (HH / 128), 256, 0, stream>>>(a);
  }

  {  // persistent scan: 32 groups x 8 ranks, group-local barriers, coherent transport
    ScanArgs s{};
    s.Pq1 = Pq1; s.Pqh = Pqh; s.Pag = Pag; s.Pih = Pih; s.Phh = Phh;
    s.obs_preT = obs_preT; s.act_bf = act_bf;
    s.h = h_bf; s.hid = hid_q; s.z = z_bf; s.a = a_buf; s.ghT = ghT;
    s.b_q1 = qb1; s.b_ghh = gbhh; s.b_qm = qbm; s.b_qs = qbs;
    s.b_ag = aggrB; s.b_gih = gbih;
    s.eps = eps; s.dout = dout; s.bar = bar;
    scan_k<<<NBLK, NTHR, 0, stream>>>(s);
  }

  {  // p_hid = elu(beliefs[0:T*B] @ pW1 + b1)
    GArgs a{};
    a.Af = dout; a.lda = HH; a.Bt = WT_p1;
    a.M = TT * BB; a.N = HH; a.K = HH; a.out_bf = p_hid; a.b_p1 = pb1;
    gemm_k<128, 128, 5, true><<<(TT * BB / 128) * (HH / 128), 256, 0, stream>>>(a);
  }
  {  // p-heads
    GArgs a{};
    a.A = p_hid; a.lda = HH; a.Bt = WT_ph;
    a.M = TT * BB; a.N = 512; a.K = HH;
    a.b_pm = pbm; a.b_ps = pbs; a.dout = dout;
    gemm_k<128, 128, 6, false><<<(TT * BB / 128) * (512 / 128), 256, 0, stream>>>(a);
  }
}

// Round 8
// 8152.107 us; speedup vs baseline: 2.5582x; 1.0149x over previous
//
#include <hip/hip_runtime.h>
#include <hip/hip_bf16.h>
#include <stdint.h>

#define TT 64
#define BB 512
#define XX 1024
#define HH 1024
#define ZZ 256
#define AA 64

#define NBLK 256
#define NTHR 512
#define ROWS 16      // rows per group
#define RPG 8        // ranks per group == XCDs; rank = physical XCC_ID

typedef __bf16 bf16;
typedef bf16 bf16x8 __attribute__((ext_vector_type(8)));
typedef float f32x4 __attribute__((ext_vector_type(4)));
typedef unsigned int u32x4 __attribute__((ext_vector_type(4)));

// d_out layout (fp32): beliefs[T+1,B,H] | q_loc | q_scale | p_loc | p_scale | z_q
#define SZ_BEL ((long)(TT + 1) * BB * HH)
#define SZ_TBZ ((long)TT * BB * ZZ)
#define OFF_QL (SZ_BEL)
#define OFF_QS (OFF_QL + SZ_TBZ)
#define OFF_PL (OFF_QL + 2 * SZ_TBZ)
#define OFF_PS (OFF_QL + 3 * SZ_TBZ)
#define OFF_ZQ (OFF_QL + 4 * SZ_TBZ)

#define GLL16(g, l)                                                         \
  __builtin_amdgcn_global_load_lds(                                         \
      (__attribute__((address_space(1))) void*)(g),                         \
      (__attribute__((address_space(3))) void*)(l), 16, 0, 0)

#define MFMA(a, b, c) __builtin_amdgcn_mfma_f32_16x16x32_bf16(a, b, c, 0, 0, 0)

#define ALOAD_U64(p) __hip_atomic_load((const unsigned long long*)(p), __ATOMIC_RELAXED, __HIP_MEMORY_SCOPE_AGENT)
#define ALOAD_U32(p) __hip_atomic_load((const unsigned*)(p), __ATOMIC_RELAXED, __HIP_MEMORY_SCOPE_AGENT)
#define ASTORE_U16(p, v) __hip_atomic_store((unsigned short*)(p), (v), __ATOMIC_RELAXED, __HIP_MEMORY_SCOPE_AGENT)
#define ASTORE_U64(p, v) __hip_atomic_store((unsigned long long*)(p), (v), __ATOMIC_RELAXED, __HIP_MEMORY_SCOPE_AGENT)
#define ASTORE_U32(p, v) __hip_atomic_store((unsigned*)(p), (v), __ATOMIC_RELAXED, __HIP_MEMORY_SCOPE_AGENT)

__device__ __forceinline__ float eluf(float x) { return x > 0.f ? x : expf(x) - 1.f; }
__device__ __forceinline__ float splusf(float x) { return fmaxf(x, 0.f) + log1pf(expf(-fabsf(x))); }
__device__ __forceinline__ float sigf(float x) { return 1.f / (1.f + expf(-x)); }
__device__ __forceinline__ unsigned short bf2u(bf16 v) { return __builtin_bit_cast(unsigned short, v); }
__device__ __forceinline__ float u2f(unsigned short u) { return (float)__builtin_bit_cast(bf16, u); }
__device__ __forceinline__ bf16x8 ldg8(const bf16* p) { return *(const bf16x8*)p; }

// 16B device-coherent (L1/L2-bypass) load
__device__ __forceinline__ void cload16(u32x4& v, const void* p) {
  asm volatile("global_load_dwordx4 %0, %1, off sc0 sc1" : "=v"(v) : "v"(p));
}

// swizzled frag read from a 16-row x 64-col LDS k-tile (2KB, row stride 128B)
__device__ __forceinline__ bf16x8 ldfrag(const char* tile, int row, int w) {
  return *(const bf16x8*)(tile + row * 128 + (w ^ ((row & 7) << 4)));
}

// Stage a 16 x C bf16 row-major panel into LDS as C/64 swizzled 2KB tiles,
// via coherent 16B loads (two-pass: issue all, waitcnt, write all).
template <int C>  // C in {1024, 256}
__device__ __forceinline__ void stage_panel16(const bf16* base, char* lds) {
  constexpr int ITER = (2 * C) / NTHR;  // 16B units / threads
  u32x4 v[ITER];
#pragma unroll
  for (int i = 0; i < ITER; ++i) {
    int u = threadIdx.x + i * NTHR;
    int ktile = u >> 7, rem = u & 127;
    int row = rem >> 3, cb = (rem & 7) * 16;
    cload16(v[i], (const char*)base + (long)row * (C * 2) + ktile * 128 + cb);
  }
  asm volatile("s_waitcnt vmcnt(0)" ::: "memory");
  __builtin_amdgcn_sched_barrier(0);
#pragma unroll
  for (int i = 0; i < ITER; ++i) {
    int u = threadIdx.x + i * NTHR;
    int ktile = u >> 7, rem = u & 127;
    int row = rem >> 3, cb = (rem & 7) * 16;
    *(u32x4*)(lds + ktile * 2048 + row * 128 + (cb ^ ((row & 7) << 4))) = v[i];
  }
}

// act tile (16 x 64, read-only input): normal cached loads
__device__ __forceinline__ void stage_act(const bf16* base, char* lds) {
  if (threadIdx.x < 128) {
    int u = threadIdx.x;
    int row = u >> 3, cb = (u & 7) * 16;
    u32x4 v = *(const u32x4*)((const char*)base + row * 128 + cb);
    *(u32x4*)(lds + row * 128 + (cb ^ ((row & 7) << 4))) = v;
  }
}

// Group-local (8-rank) barrier: per-rank arrival words (one line/group) + go.
__device__ __forceinline__ void gbar(unsigned* arr, unsigned* go, int rank, unsigned gen) {
  __syncthreads();
  if (rank == 0) {
    if (threadIdx.x > 0 && threadIdx.x < RPG) {
      while (ALOAD_U32(&arr[threadIdx.x]) < gen) __builtin_amdgcn_s_sleep(2);
    }
    if (threadIdx.x == 0) ASTORE_U32(go, gen);
  } else if (threadIdx.x == 0) {
    ASTORE_U32(&arr[rank], gen);
    while (ALOAD_U32(go) < gen) __builtin_amdgcn_s_sleep(2);
  }
  __syncthreads();
  asm volatile("" ::: "memory");
}

struct ScanArgs {
  const bf16 *Pq1, *Pqh, *Pag, *Pih, *Phh;  // frag-linear packed weights
  const bf16 *obs_preT, *act_bf;
  bf16 *h, *hid, *z, *a, *ghT;
  const float *b_q1, *b_ghh, *b_qm, *b_qs, *b_ag, *b_gih;
  const float* eps;
  float* dout;
  unsigned* bar;  // [0..1023] arrive, [1024..2047] go, [2048..] per-XCD tickets
};

__global__ __launch_bounds__(NTHR, 2) void scan_k(ScanArgs s) {
  // 96KB forces 1 block/CU -> exactly 32 blocks per XCD (grid = 256 = #CUs).
  __shared__ __align__(16) char smem[98304];
  const int tid = threadIdx.x;
  const int wid = tid >> 6, lane = tid & 63;
  const int lr = lane & 15, lk = lane >> 4;

  // rank = physical XCD (weights L2-resident by construction);
  // group = per-XCD arrival ticket (0..31).
  int xcd;
  asm volatile("s_getreg_b32 %0, hwreg(HW_REG_XCC_ID)" : "=s"(xcd));
  xcd &= 7;
  __shared__ int sgr;
  if (tid == 0) sgr = (int)atomicAdd(&s.bar[2048 + xcd * 64], 1u);
  __syncthreads();
  const int rank = xcd;
  const int g = sgr;

  unsigned gen = 0;
  unsigned* arr = s.bar + g * 32;
  unsigned* go = s.bar + 1024 + g * 32;

  bf16* hg = s.h + (long)g * ROWS * HH;
  bf16* hid_g = s.hid + (long)g * ROWS * HH;
  bf16* zg = s.z + (long)g * ROWS * ZZ;
  bf16* ag = s.a + (long)g * ROWS * HH;
  bf16* ghT_g = s.ghT + (long)g * 3072 * ROWS;

  float hreg[4] = {0.f, 0.f, 0.f, 0.f};

  for (int t = 0; t < TT; ++t) {
    // ===== P1: ranks 0-1: hid = elu(h@Wq1h + obs + b) (512 cols each)
    //           ranks 2-7: ghT = bf16(h@Whh)           (512 cols each)
    {
      stage_panel16<1024>(hg, smem);
      __syncthreads();
      const bool isHid = rank < 2;
      const int fb = (isHid ? rank : rank - 2) * 32 + wid * 4;
      const bf16* P = isHid ? s.Pq1 : s.Phh;
      const bf16* bp[4];
#pragma unroll
      for (int nj = 0; nj < 4; ++nj) bp[nj] = P + ((long)(fb + nj) * 32) * 512 + lane * 8;
      bf16x8 br[2][4];
#pragma unroll
      for (int nj = 0; nj < 4; ++nj) { br[0][nj] = ldg8(bp[nj]); br[1][nj] = ldg8(bp[nj] + 512); }
      f32x4 acc[4] = {};
#pragma unroll
      for (int kk = 0; kk < 32; ++kk) {
        const int sl = kk & 1;
        bf16x8 a = ldfrag(smem + (kk >> 1) * 2048, lr, (kk & 1) * 64 + lk * 16);
#pragma unroll
        for (int nj = 0; nj < 4; ++nj) acc[nj] = MFMA(a, br[sl][nj], acc[nj]);
        if (kk + 2 < 32) {
#pragma unroll
          for (int nj = 0; nj < 4; ++nj) br[sl][nj] = ldg8(bp[nj] + (kk + 2) * 512);
        }
      }
      if (isHid) {
        const int colb = rank * 512 + wid * 64;
#pragma unroll
        for (int nj = 0; nj < 4; ++nj) {
          const int col = colb + nj * 16 + lr;
          const float bq = s.b_q1[col];
          unsigned long long o8 = *(const unsigned long long*)
              &s.obs_preT[((long)t * HH + col) * BB + g * ROWS + lk * 4];
#pragma unroll
          for (int r = 0; r < 4; ++r) {
            float x = acc[nj][r] + bq + u2f((unsigned short)(o8 >> (16 * r)));
            ASTORE_U16(&hid_g[(lk * 4 + r) * HH + col], bf2u((bf16)eluf(x)));
          }
        }
      } else {
        const int colb = (rank - 2) * 512 + wid * 64;
#pragma unroll
        for (int nj = 0; nj < 4; ++nj) {
          const int cg = colb + nj * 16 + lr;
          unsigned long long pk = 0;
#pragma unroll
          for (int r = 0; r < 4; ++r)
            pk |= (unsigned long long)bf2u((bf16)acc[nj][r]) << (16 * r);
          ASTORE_U64(&ghT_g[(long)cg * ROWS + lk * 4], pk);
        }
      }
    }
    gbar(arr, go, rank, ++gen);

    // ===== P2: q-heads dual (loc|scale) + rsample; rank covers 32 j, 4 waves
    {
      stage_panel16<1024>(hid_g, smem);
      __syncthreads();
      if (wid < 4) {
        const int f = rank * 4 + wid;
        const bf16* bp = s.Pqh + ((long)f * 32) * 512 + lane * 8;
        bf16x8 br[4];
#pragma unroll
        for (int p = 0; p < 4; ++p) br[p] = ldg8(bp + p * 512);
        f32x4 acc = {};
#pragma unroll
        for (int kk = 0; kk < 32; ++kk) {
          bf16x8 a = ldfrag(smem + (kk >> 1) * 2048, lr, (kk & 1) * 64 + lk * 16);
          acc = MFMA(a, br[kk & 3], acc);
          if (kk + 4 < 32) br[kk & 3] = ldg8(bp + (kk + 4) * 512);
        }
        const int j0 = rank * 32 + wid * 8;
        const int jj = j0 + (lr & 7);
        const float bias = (lr < 8) ? s.b_qm[jj] : s.b_qs[jj];
#pragma unroll
        for (int r = 0; r < 4; ++r) {
          const int rl = lk * 4 + r;
          const long grow = (long)g * ROWS + rl;
          const long o = ((long)t * BB + grow) * ZZ + jj;
          float myv = acc[r] + bias;
          float sp = splusf(myv);
          float sc = __shfl(sp, lane + 8, 64);
          if (lr < 8) {
            float zv = myv + sc * s.eps[o];
            s.dout[OFF_QL + o] = myv;
            s.dout[OFF_ZQ + o] = zv;
            ASTORE_U16(&zg[rl * ZZ + jj], bf2u((bf16)zv));
          } else {
            s.dout[OFF_QS + o] = sp;
          }
        }
      }
    }
    gbar(arr, go, rank, ++gen);

    // ===== P3: a = elu([z|act]@aggrW + b); rank covers 128 cols, K=320
    {
      stage_panel16<256>(zg, smem);
      stage_act(s.act_bf + ((long)t * BB + (long)g * ROWS) * AA, smem + 4 * 2048);
      __syncthreads();
      const int f = rank * 8 + wid;
      const bf16* bp = s.Pag + ((long)f * 10) * 512 + lane * 8;
      bf16x8 br[10];
#pragma unroll
      for (int p = 0; p < 10; ++p) br[p] = ldg8(bp + (long)p * 512);
      f32x4 acc = {};
#pragma unroll
      for (int kk = 0; kk < 10; ++kk) {
        bf16x8 a = ldfrag(smem + (kk >> 1) * 2048, lr, (kk & 1) * 64 + lk * 16);
        acc = MFMA(a, br[kk], acc);
      }
      const int col = rank * 128 + wid * 16 + lr;
      const float ba = s.b_ag[col];
#pragma unroll
      for (int r = 0; r < 4; ++r)
        ASTORE_U16(&ag[(lk * 4 + r) * HH + col], bf2u((bf16)eluf(acc[r] + ba)));
    }
    gbar(arr, go, rank, ++gen);

    // ===== P4: gi = a@Wih (3 gates x 16 j per wave) + GRU fuse; h in regs
    {
      const int j = rank * 128 + wid * 16 + lr;
      unsigned long long ghp0 = ALOAD_U64(&ghT_g[(long)(0 * HH + j) * ROWS + lk * 4]);
      unsigned long long ghp1 = ALOAD_U64(&ghT_g[(long)(1 * HH + j) * ROWS + lk * 4]);
      unsigned long long ghp2 = ALOAD_U64(&ghT_g[(long)(2 * HH + j) * ROWS + lk * 4]);
      stage_panel16<1024>(ag, smem);
      __syncthreads();
      const int fb = rank * 8 + wid;
      const bf16* bp0 = s.Pih + ((long)(0 * 64 + fb) * 32) * 512 + lane * 8;
      const bf16* bp1 = s.Pih + ((long)(1 * 64 + fb) * 32) * 512 + lane * 8;
      const bf16* bp2 = s.Pih + ((long)(2 * 64 + fb) * 32) * 512 + lane * 8;
      bf16x8 b0[2], b1[2], b2[2];
      b0[0] = ldg8(bp0); b0[1] = ldg8(bp0 + 512);
      b1[0] = ldg8(bp1); b1[1] = ldg8(bp1 + 512);
      b2[0] = ldg8(bp2); b2[1] = ldg8(bp2 + 512);
      f32x4 gi0 = {}, gi1 = {}, gi2 = {};
#pragma unroll
      for (int kk = 0; kk < 32; ++kk) {
        const int sl = kk & 1;
        bf16x8 a = ldfrag(smem + (kk >> 1) * 2048, lr, (kk & 1) * 64 + lk * 16);
        gi0 = MFMA(a, b0[sl], gi0);
        gi1 = MFMA(a, b1[sl], gi1);
        gi2 = MFMA(a, b2[sl], gi2);
        if (kk + 2 < 32) {
          b0[sl] = ldg8(bp0 + (kk + 2) * 512);
          b1[sl] = ldg8(bp1 + (kk + 2) * 512);
          b2[sl] = ldg8(bp2 + (kk + 2) * 512);
        }
      }
      const float bi0 = s.b_gih[j], bi1 = s.b_gih[HH + j], bi2 = s.b_gih[2 * HH + j];
      const float bh0 = s.b_ghh[j], bh1 = s.b_ghh[HH + j], bh2 = s.b_ghh[2 * HH + j];
#pragma unroll
      for (int r = 0; r < 4; ++r) {
        const int rl = lk * 4 + r;
        float rr = sigf(gi0[r] + bi0 + u2f((unsigned short)(ghp0 >> (16 * r))) + bh0);
        float zz = sigf(gi1[r] + bi1 + u2f((unsigned short)(ghp1 >> (16 * r))) + bh1);
        float nn = tanhf(gi2[r] + bi2 + rr * (u2f((unsigned short)(ghp2 >> (16 * r))) + bh2));
        float hnew = (1.f - zz) * nn + zz * hreg[r];
        hreg[r] = hnew;
        ASTORE_U16(&hg[rl * HH + j], bf2u((bf16)hnew));
        s.dout[(long)(t + 1) * BB * HH + ((long)g * ROWS + rl) * HH + j] = hnew;
      }
    }
    gbar(arr, go, rank, ++gen);
  }
}

// ---------------- weight packing (frag-linear) -------------------------------
// dst[((f*kts + kt)*64 + l)*8 + e] = W[(row0 + kt*32 + (l>>4)*8 + e)*ld + col],
// col = f*16 + (l&15)
__global__ void pack16(const float* __restrict__ W, bf16* __restrict__ dst,
                       int ld, int row0, int kts, int kmax, long total) {
  long idx = (long)blockIdx.x * 256 + threadIdx.x;
  if (idx >= total) return;
  int l = (int)(idx & 63);
  long fk = idx >> 6;
  int kt = (int)(fk % kts);
  int f = (int)(fk / kts);
  int col = f * 16 + (l & 15);
  int k = kt * 32 + (l >> 4) * 8;
  bf16x8 v;
#pragma unroll
  for (int e = 0; e < 8; ++e) {
    int kk = k + e;
    v[e] = (bf16)((kk < kmax) ? W[(long)(row0 + kk) * ld + col] : 0.f);
  }
  *(bf16x8*)&dst[idx * 8] = v;
}

// dual loc/scale frag: cols lr<8 from Wm[:, f*8..], lr>=8 from Ws[:, f*8..]
__global__ void pack_qh(const float* __restrict__ Wm, const float* __restrict__ Ws,
                        bf16* __restrict__ dst) {
  long idx = (long)blockIdx.x * 256 + threadIdx.x;  // 32*32*64
  int l = (int)(idx & 63);
  long fk = idx >> 6;
  int f = (int)(fk >> 5);
  int k = (int)((fk & 31) * 32) + (l >> 4) * 8;
  const float* W = ((l & 15) < 8) ? Wm : Ws;
  int col = f * 8 + (l & 7);
  bf16x8 v;
#pragma unroll
  for (int e = 0; e < 8; ++e) v[e] = (bf16)W[(long)(k + e) * 256 + col];
  *(bf16x8*)&dst[idx * 8] = v;
}

// ---------------- batched GEMMs (prep / tails) ----------------

struct GArgs {
  const bf16* A; const float* Af;
  long lda;
  const bf16* Bt;
  int M, N, K;
  const float *b_p1, *b_pm, *b_ps;
  bf16* out_bf;
  float* dout;
};

// EPI: 5 = elu+bias -> bf16   6 = p-heads -> d_out   7 = bf16 transposed [t][col][row]
template <int BM, int BN, int EPI, bool AF32>
__global__ __launch_bounds__(256) void gemm_k(GArgs g) {
  constexpr int BK = 32;
  constexpr int WTM = BM / 2, WTN = BN / 2;
  constexpr int MR = WTM / 16, NR = WTN / 16;
  constexpr int CA = BM * 4 / 256, CB = BN * 4 / 256;
  __shared__ bf16 sA[BM * BK];
  __shared__ bf16 sB[BN * BK];
  const int nbm = g.M / BM;
  const int bm = blockIdx.x % nbm, bn = blockIdx.x / nbm;
  const int m0 = bm * BM, n0 = bn * BN;
  const int tid = threadIdx.x;
  const int wid = tid >> 6, lane = tid & 63;
  const int wm = wid & 1, wn = wid >> 1;
  const int lr = lane & 15, lk = lane >> 4;

  f32x4 acc[MR][NR] = {};

  for (int k0 = 0; k0 < g.K; k0 += BK) {
    __syncthreads();
    if constexpr (AF32) {
#pragma unroll
      for (int i = 0; i < CA; i++) {
        int c = tid + i * 256, row = c >> 2, kc = c & 3;
        const float* sp = g.Af + (long)(m0 + row) * g.lda + k0 + kc * 8;
        float4 v0 = *(const float4*)sp;
        float4 v1 = *(const float4*)(sp + 4);
        bf16x8 p;
        p[0] = (bf16)v0.x; p[1] = (bf16)v0.y; p[2] = (bf16)v0.z; p[3] = (bf16)v0.w;
        p[4] = (bf16)v1.x; p[5] = (bf16)v1.y; p[6] = (bf16)v1.z; p[7] = (bf16)v1.w;
        *(bf16x8*)&sA[c * 8] = p;
      }
    } else {
#pragma unroll
      for (int i = 0; i < CA; i++) {
        int c = tid + i * 256, row = c >> 2, kc = c & 3;
        GLL16(g.A + (long)(m0 + row) * g.lda + k0 + kc * 8, &sA[c * 8]);
      }
    }
#pragma unroll
    for (int i = 0; i < CB; i++) {
      int c = tid + i * 256, row = c >> 2, kc = c & 3;
      GLL16(g.Bt + (long)(n0 + row) * g.K + k0 + kc * 8, &sB[c * 8]);
    }
    __syncthreads();
    bf16x8 af[MR];
#pragma unroll
    for (int mi = 0; mi < MR; mi++)
      af[mi] = *(const bf16x8*)&sA[(wm * WTM + mi * 16 + lr) * BK + lk * 8];
#pragma unroll
    for (int nj = 0; nj < NR; nj++) {
      bf16x8 bfr = *(const bf16x8*)&sB[(wn * WTN + nj * 16 + lr) * BK + lk * 8];
#pragma unroll
      for (int mi = 0; mi < MR; mi++)
        acc[mi][nj] = MFMA(af[mi], bfr, acc[mi][nj]);
    }
  }

#pragma unroll
  for (int mi = 0; mi < MR; mi++)
#pragma unroll
    for (int nj = 0; nj < NR; nj++)
#pragma unroll
      for (int r = 0; r < 4; r++) {
        const int row = m0 + wm * WTM + mi * 16 + lk * 4 + r;
        const int col = n0 + wn * WTN + nj * 16 + lr;
        float v = acc[mi][nj][r];
        if constexpr (EPI == 7) {
          g.out_bf[((long)(row >> 9) * HH + col) * BB + (row & 511)] = (bf16)v;
        } else if constexpr (EPI == 5) {
          g.out_bf[(long)row * g.N + col] = (bf16)eluf(v + g.b_p1[col]);
        } else {
          int region = col >> 8, j = col & 255;
          float x = v + (region ? g.b_ps[j] : g.b_pm[j]);
          if (region) x = splusf(x);
          g.dout[(region ? OFF_PS : OFF_PL) + (long)row * ZZ + j] = x;
        }
      }
}

// dst[n*K + k] = bf16(src[(k + k_off)*ld + n])
__global__ void transpose_cvt(const float* __restrict__ src, bf16* __restrict__ dst,
                              int K, int N, int ld, int k_off) {
  __shared__ float tile[32][33];
  const int nb = blockIdx.x * 32, kb = blockIdx.y * 32;
  const int tx = threadIdx.x, ty = threadIdx.y;
#pragma unroll
  for (int j = 0; j < 32; j += 8)
    tile[ty + j][tx] = src[(long)(kb + ty + j + k_off) * ld + nb + tx];
  __syncthreads();
#pragma unroll
  for (int j = 0; j < 32; j += 8)
    dst[(long)(nb + ty + j) * K + kb + tx] = (bf16)tile[tx][ty + j];
}

__global__ void cvt_bf16(const float* __restrict__ src, bf16* __restrict__ dst, long n) {
  long i = ((long)blockIdx.x * blockDim.x + threadIdx.x) * 4;
  if (i < n) {
    float4 v = *(const float4*)(src + i);
    dst[i] = (bf16)v.x; dst[i + 1] = (bf16)v.y;
    dst[i + 2] = (bf16)v.z; dst[i + 3] = (bf16)v.w;
  }
}

__global__ void init_k(bf16* hbf, float* dout) {
  int i = blockIdx.x * 256 + threadIdx.x;
  hbf[i] = (bf16)0.f;
  dout[i] = 0.f;  // beliefs[0] = h0 = 0
}

extern "C" void kernel_launch(void* const* d_in, const int* in_sizes, int n_in,
                              void* d_out, int out_size, void* d_ws, size_t ws_size,
                              hipStream_t stream) {
  const float* obs  = (const float*)d_in[0];
  const float* act  = (const float*)d_in[1];
  const float* eps  = (const float*)d_in[2];
  const float* aggrW = (const float*)d_in[3];
  const float* aggrB = (const float*)d_in[4];
  const float* gWih = (const float*)d_in[5];
  const float* gWhh = (const float*)d_in[6];
  const float* gbih = (const float*)d_in[7];
  const float* gbhh = (const float*)d_in[8];
  const float* qW1  = (const float*)d_in[9];
  const float* qb1  = (const float*)d_in[10];
  const float* qWm  = (const float*)d_in[11];
  const float* qbm  = (const float*)d_in[12];
  const float* qWs  = (const float*)d_in[13];
  const float* qbs  = (const float*)d_in[14];
  const float* pW1  = (const float*)d_in[15];
  const float* pb1  = (const float*)d_in[16];
  const float* pWm  = (const float*)d_in[17];
  const float* pbm  = (const float*)d_in[18];
  const float* pWs  = (const float*)d_in[19];
  const float* pbs  = (const float*)d_in[20];
  float* dout = (float*)d_out;

  char* w = (char*)d_ws;
  size_t off = 0;
  auto alloc = [&](size_t bytes) -> char* {
    char* r = w + off;
    off = (off + bytes + 255) & ~(size_t)255;
    return r;
  };
  bf16* Pq1 = (bf16*)alloc((size_t)64 * 32 * 512 * 2);
  bf16* Pqh = (bf16*)alloc((size_t)32 * 32 * 512 * 2);
  bf16* Pag = (bf16*)alloc((size_t)64 * 10 * 512 * 2);
  bf16* Pih = (bf16*)alloc((size_t)192 * 32 * 512 * 2);
  bf16* Phh = (bf16*)alloc((size_t)192 * 32 * 512 * 2);
  bf16* WT_qobs = (bf16*)alloc((size_t)XX * HH * 2);
  bf16* WT_p1  = (bf16*)alloc((size_t)HH * HH * 2);
  bf16* WT_ph  = (bf16*)alloc((size_t)512 * HH * 2);
  bf16* obs_preT = (bf16*)alloc((size_t)TT * HH * BB * 2);  // p_hid alias after scan
  bf16* p_hid  = obs_preT;
  bf16* act_bf = (bf16*)alloc((size_t)TT * BB * AA * 2);
  bf16* h_bf   = (bf16*)alloc((size_t)BB * HH * 2);
  bf16* hid_q  = (bf16*)alloc((size_t)BB * HH * 2);
  bf16* z_bf   = (bf16*)alloc((size_t)BB * ZZ * 2);
  bf16* a_buf  = (bf16*)alloc((size_t)BB * HH * 2);
  bf16* ghT    = (bf16*)alloc((size_t)BB * 3 * HH * 2);  // [g][3072][16] bf16
  unsigned* bar = (unsigned*)alloc(16384);
  (void)ws_size; (void)in_sizes; (void)n_in; (void)out_size;

  hipMemsetAsync(bar, 0, 16384, stream);

  pack16<<<512, 256, 0, stream>>>(qW1, Pq1, 1024, 1024, 32, 1024, 64L * 32 * 64);
  pack16<<<1536, 256, 0, stream>>>(gWhh, Phh, 3072, 0, 32, 1024, 192L * 32 * 64);
  pack16<<<1536, 256, 0, stream>>>(gWih, Pih, 3072, 0, 32, 1024, 192L * 32 * 64);
  pack16<<<160, 256, 0, stream>>>(aggrW, Pag, 1024, 0, 10, 320, 64L * 10 * 64);
  pack_qh<<<256, 256, 0, stream>>>(qWm, qWs, Pqh);

  dim3 tb(32, 8);
  transpose_cvt<<<dim3(32, 32), tb, 0, stream>>>(qW1, WT_qobs, 1024, 1024, 1024, 0);
  transpose_cvt<<<dim3(32, 32), tb, 0, stream>>>(pW1, WT_p1, 1024, 1024, 1024, 0);
  transpose_cvt<<<dim3(8, 32), tb, 0, stream>>>(pWm, WT_ph, 1024, 256, 256, 0);
  transpose_cvt<<<dim3(8, 32), tb, 0, stream>>>(pWs, WT_ph + 256 * 1024, 1024, 256, 256, 0);
  cvt_bf16<<<TT * BB * AA / 4 / 256, 256, 0, stream>>>(act, act_bf, (long)TT * BB * AA);
  init_k<<<BB * HH / 256, 256, 0, stream>>>(h_bf, dout);

  {  // obs_preT = (obs @ qW1[:X]) transposed-store
    GArgs a{};
    a.Af = obs; a.lda = XX; a.Bt = WT_qobs;
    a.M = TT * BB; a.N = HH; a.K = XX; a.out_bf = obs_preT;
    gemm_k<128, 128, 7, true><<<(TT * BB / 128) * (HH / 128), 256, 0, stream>>>(a);
  }

  {  // persistent scan: rank = physical XCD, group = per-XCD ticket
    ScanArgs s{};
    s.Pq1 = Pq1; s.Pqh = Pqh; s.Pag = Pag; s.Pih = Pih; s.Phh = Phh;
    s.obs_preT = obs_preT; s.act_bf = act_bf;
    s.h = h_bf; s.hid = hid_q; s.z = z_bf; s.a = a_buf; s.ghT = ghT;
    s.b_q1 = qb1; s.b_ghh = gbhh; s.b_qm = qbm; s.b_qs = qbs;
    s.b_ag = aggrB; s.b_gih = gbih;
    s.eps = eps; s.dout = dout; s.bar = bar;
    scan_k<<<NBLK, NTHR, 0, stream>>>(s);
  }

  {  // p_hid = elu(beliefs[0:T*B] @ pW1 + b1)
    GArgs a{};
    a.Af = dout; a.lda = HH; a.Bt = WT_p1;
    a.M = TT * BB; a.N = HH; a.K = HH; a.out_bf = p_hid; a.b_p1 = pb1;
    gemm_k<128, 128, 5, true><<<(TT * BB / 128) * (HH / 128), 256, 0, stream>>>(a);
  }
  {  // p-heads
    GArgs a{};
    a.A = p_hid; a.lda = HH; a.Bt = WT_ph;
    a.M = TT * BB; a.N = 512; a.K = HH;
    a.b_pm = pbm; a.b_ps = pbs; a.dout = dout;
    gemm_k<128, 128, 6, false><<<(TT * BB / 128) * (512 / 128), 256, 0, stream>>>(a);
  }
}